// Round 1
// baseline (1017.548 us; speedup 1.0000x reference)
//
#include <hip/hip_runtime.h>
#include <math.h>

#define DEV __device__ __forceinline__

typedef __attribute__((ext_vector_type(8))) short short8;
typedef __attribute__((ext_vector_type(4))) short short4v;
typedef __attribute__((ext_vector_type(4))) float f32x4;
typedef __attribute__((ext_vector_type(2))) unsigned uint2v;

// LDS rows: 128 shorts (256 B = 16 chunks of 16 B). Bank conflicts killed by
// XOR-swizzling the 16B-chunk index with (row & 7) on BOTH write and read
// (T2). Full-wave ds_read_b128 is then exactly 8 words/bank = minimum.
#define RS 128
#define ROWB (16 * RS * 2)   // 4096 B per 16-row tile

DEV short f2bf(float f) {
    unsigned u = __builtin_bit_cast(unsigned, f);
    unsigned r = (u + 0x7fffu + ((u >> 16) & 1u)) >> 16;
    return (short)r;
}

#if __has_builtin(__builtin_amdgcn_cvt_pk_bf16_f32)
DEV unsigned pk2bf(float a, float b) {
    auto v = __builtin_amdgcn_cvt_pk_bf16_f32(a, b);
    return __builtin_bit_cast(unsigned, v);
}
#else
DEV unsigned pk2bf(float a, float b) {
    return ((unsigned)(unsigned short)f2bf(a)) |
           (((unsigned)(unsigned short)f2bf(b)) << 16);
}
#endif

DEV float bfu(short s) {
    unsigned u = ((unsigned)(unsigned short)s) << 16;
    return __builtin_bit_cast(float, u);
}

// LDS-only barrier: lgkmcnt(0) + s_barrier, NO vmcnt drain. __syncthreads()
// emits s_waitcnt vmcnt(0) before s_barrier, which would drain the
// register-prefetch gather loads at every pass boundary and kill the T14
// overlap. All intra-block communication here is via LDS, so lgkm suffices.
DEV void barrier_lgkm() {
    asm volatile("s_waitcnt lgkmcnt(0)" ::: "memory");
    __builtin_amdgcn_s_barrier();
}

// ---------------------------------------------------------------------------
// emb f32 [V][100] -> bf16 [V][112], cols 100..111 zeroed. 8 rows/block.
// ---------------------------------------------------------------------------
__global__ __launch_bounds__(256) void emb_cvt_kernel(
    const float* __restrict__ emb, short* __restrict__ embT) {
    int t = threadIdx.x;
    int row = blockIdx.x * 8 + (t >> 5);
    int c4 = t & 31;
    if (c4 >= 28) return;
    short4v v = {0, 0, 0, 0};
    if (c4 < 25) {
        f32x4 e = *(const f32x4*)&emb[row * 100 + c4 * 4];
#pragma unroll
        for (int r = 0; r < 4; ++r) v[r] = f2bf(e[r]);
    }
    *(short4v*)&embT[row * 112 + c4 * 4] = v;
}

// ---------------------------------------------------------------------------
// Pack conv weights into MFMA A-fragment order.
// NEW layout: [fb*64 + lane][ks] contiguous in ks -> the K-loop's A-loads are
// ONE base address per (mt) + imm offsets ks*16B (0..144), instead of
// ks-strided 7168B addresses recomputed per load.
// mode 0 (3-tap): 13 octets per tap; K = 320 (10 ks).
// mode 1 (conv3 loc half): kappa = c (cols 100..199 of w[100][200]), K 128.
// ---------------------------------------------------------------------------
__global__ __launch_bounds__(64) void pack_all_kernel(
    const float* __restrict__ c1w, const float* __restrict__ c2w,
    const float* __restrict__ liw, const float* __restrict__ c3w,
    short* __restrict__ A1, short* __restrict__ A2,
    short* __restrict__ A3, short* __restrict__ A4) {
    int bx = blockIdx.x;
    const float* w; short* dst; int mode, lbx;
    if (bx < 70)       { w = c1w; dst = A1; mode = 0; lbx = bx; }
    else if (bx < 140) { w = c2w; dst = A2; mode = 0; lbx = bx - 70; }
    else if (bx < 210) { w = liw; dst = A3; mode = 0; lbx = bx - 140; }
    else               { w = c3w; dst = A4; mode = 1; lbx = bx - 210; }
    int lane = threadIdx.x;
    int fblk = lbx % 7, ksb = lbx / 7;
    int f = fblk * 16 + (lane & 15);
    int kb = ksb * 32 + (lane >> 4) * 8;
    int nks = (mode == 0) ? 10 : 4;
    short8 v;
#pragma unroll
    for (int j = 0; j < 8; ++j) {
        int kk = kb + j;
        float val = 0.f;
        if (f < 100) {
            if (mode == 0) {
                int oct = kk >> 3, dk = oct / 13;
                int c = (oct - 13 * dk) * 8 + (kk & 7);
                if (dk < 3 && c < 100) val = w[(f * 100 + c) * 3 + dk];
            } else {
                if (kk < 100) val = w[f * 200 + 100 + kk];
            }
        }
        v[j] = f2bf(val);
    }
    *(short8*)&dst[((fblk * 64 + lane) * nks + ksb) * 8] = v;
}

// ---------------------------------------------------------------------------
// One 3-tap conv pass, BALANCED tile: this wave owns mt [MTB,MTB+MT) x
// nt [NTB,NTB+NT). Accumulator init = bias. CLAMPL: the nt==4 tile reads
// clamped rows (feeds only discarded outputs). EDGE: l-range zeroing only in
// edge tiles. POOL: relu partial sums for l in [l0,l0+64) -> hpart_slot[112].
// bofs[] carry the chunk XOR swizzle (key = row&7; 16*nt offset doesn't
// affect row&7, so one bofs serves all nt).
// ---------------------------------------------------------------------------
template<int MT, int NT, int MTB, int NTB, bool CLAMPL, bool POOL,
         bool TO_GLOBAL, bool EDGE>
DEV void ctap(const short* __restrict__ Ap, const short* s_src, short* s_dst,
              short* __restrict__ gout, const int* bofs, const int* bofs4,
              const float* __restrict__ bias, int row0l, int l0,
              float* __restrict__ hpart_slot, int lane) {
    const int q = lane >> 4, n = lane & 15;
    const int skey = n & 7;
    const f32x4 z4 = {0.f, 0.f, 0.f, 0.f};
    f32x4 acc[MT][NT];
#pragma unroll
    for (int mt = 0; mt < MT; ++mt) {
        int fb = (MTB + mt) * 16 + q * 4;
        f32x4 bs = (fb < 100) ? *(const f32x4*)&bias[fb] : z4;
#pragma unroll
        for (int nt = 0; nt < NT; ++nt) acc[mt][nt] = bs;
    }
#pragma unroll
    for (int ks = 0; ks < 10; ++ks) {
        short8 a[MT];
#pragma unroll
        for (int mt = 0; mt < MT; ++mt)
            a[mt] = *(const short8*)&Ap[(((MTB + mt) * 64 + lane) * 10 + ks) * 8];
        const char* bp = (const char*)s_src + bofs[ks];
        short8 bf[NT];
#pragma unroll
        for (int nt = 0; nt < NT; ++nt) {
            if (CLAMPL && (NTB + nt) == 4)
                bf[nt] = *(const short8*)((const char*)s_src + bofs4[ks]);
            else
                bf[nt] = *(const short8*)(bp + (NTB + nt) * ROWB);
        }
#pragma unroll
        for (int mt = 0; mt < MT; ++mt)
#pragma unroll
            for (int nt = 0; nt < NT; ++nt)
                acc[mt][nt] = __builtin_amdgcn_mfma_f32_16x16x32_bf16(
                    a[mt], bf[nt], acc[mt][nt], 0, 0, 0);
    }
    f32x4 ps[MT];
    if constexpr (POOL) {
#pragma unroll
        for (int mt = 0; mt < MT; ++mt) ps[mt] = z4;
    }
#pragma unroll
    for (int nt = 0; nt < NT; ++nt) {
        const int j = (NTB + nt) * 16 + n;
        const int l = row0l + j;
        bool lok = true;
        if constexpr (EDGE) lok = ((unsigned)l < 512u);
        const bool pok = POOL && (l >= l0) && (l < l0 + 64);
#pragma unroll
        for (int mt = 0; mt < MT; ++mt) {
            const int fb = (MTB + mt) * 16 + q * 4;
            f32x4 v;
#pragma unroll
            for (int r = 0; r < 4; ++r) {
                v[r] = fmaxf(acc[mt][nt][r], 0.f);
                if constexpr (EDGE) v[r] = lok ? v[r] : 0.f;
            }
            if constexpr (POOL) {
                if (pok) {
#pragma unroll
                    for (int r = 0; r < 4; ++r) ps[mt][r] += v[r];
                }
            }
            uint2v pk;
            pk[0] = pk2bf(v[0], v[1]); pk[1] = pk2bf(v[2], v[3]);
            if constexpr (TO_GLOBAL) {
                *(uint2v*)&gout[j * 112 + fb] = pk;
            } else {
                if ((NTB + nt) < 4 || n < 6) {    // store rows j < 70 only
                    const int cch = (MTB + mt) * 2 + (q >> 1);
                    *(uint2v*)&s_dst[j * RS + ((cch ^ skey) << 3) + (q & 1) * 4] = pk;
                }
            }
        }
    }
    if constexpr (POOL) {
#pragma unroll
        for (int mt = 0; mt < MT; ++mt)
#pragma unroll
            for (int off = 1; off <= 8; off <<= 1)
#pragma unroll
                for (int r = 0; r < 4; ++r)
                    ps[mt][r] += __shfl_xor(ps[mt][r], off, 64);
        if (n == 0) {
#pragma unroll
            for (int mt = 0; mt < MT; ++mt)
                *(f32x4*)&hpart_slot[(MTB + mt) * 16 + q * 4] = ps[mt];
        }
    }
}

// Register-prefetch staging (T14 issue-early / write-late). Slot coords are
// recomputed from tid (cheap VALU) to keep VGPR pressure at the 2x5 short8
// data buffers only (~40 VGPRs).
DEV void issue_stage(short8* sv, const int* s_xidx,
                     const short* __restrict__ embT, int tid, int bx, int it) {
#pragma unroll
    for (int p = 0; p < 5; ++p) {
        int idx = tid + p * 256;
        int j = idx >> 4, c8 = idx & 15;
        short8 v = {0, 0, 0, 0, 0, 0, 0, 0};
        if (j < 70 && c8 < 14) {
            int li = it * 64 + j;                 // index into s_xidx window
            int lg = bx * 256 + li - 3;           // global l
            if (lg >= 0 && lg < 512) {
                int row = s_xidx[li];
                v = *(const short8*)&embT[(size_t)row * 112 + c8 * 8];
            }
        }
        sv[p] = v;
    }
}

DEV void write_stage(const short8* sv, short* s_e, int tid) {
#pragma unroll
    for (int p = 0; p < 5; ++p) {
        int idx = tid + p * 256;
        int j = idx >> 4, c8 = idx & 15;
        if (j < 70 && c8 < 14)
            *(short8*)&s_e[j * RS + ((c8 ^ (j & 7)) << 3)] = sv[p];
    }
}

// ---------------------------------------------------------------------------
// Fused conv1 -> conv2 -> li. PERSISTENT 4-TILE BLOCKS: grid (2,512) = 1024
// blocks = exactly 4/CU. Each block runs tiles t = bx*4..bx*4+3; the next
// tile's embT gather is issued into registers at the top of the current
// tile's compute and written to LDS after pass3 -- gather latency hides under
// ~3 passes of MFMA instead of being serially exposed per tile. Raw
// lgkm-barriers keep the prefetch in flight across pass boundaries.
// LDS 2*72*RS*2 + 264*4 = 37920 B -> 4 blocks/CU.
// ---------------------------------------------------------------------------
__global__ __launch_bounds__(256, 4) void fused_conv_kernel(
    const int* __restrict__ xidx, const short* __restrict__ embT,
    const short* __restrict__ A1, const short* __restrict__ A2,
    const short* __restrict__ A3,
    const float* __restrict__ b1, const float* __restrict__ b2,
    const float* __restrict__ b3,
    short* __restrict__ locT, float* __restrict__ hpart) {
    extern __shared__ char smem[];
    short* s_e = (short*)smem;                        // [72][RS], later c2
    short* s_h = (short*)(smem + 72 * RS * 2);        // [72][RS]
    int* s_xidx = (int*)(smem + 2 * 72 * RS * 2);     // [264]
    const int tid = threadIdx.x;
    const int b = blockIdx.y, bx = blockIdx.x;
    const int lane = tid & 63, wv = tid >> 6;
    const int q = lane >> 4, n = lane & 15;

    // stage xidx window [bx*256-3, bx*256+260] once per block
    {
        int g = bx * 256 - 3 + tid;
        s_xidx[tid] = ((unsigned)g < 512u) ? xidx[b * 512 + g] : 0;
        if (tid < 8) {
            int i2 = 256 + tid, g2 = bx * 256 - 3 + i2;
            s_xidx[i2] = ((unsigned)g2 < 512u) ? xidx[b * 512 + g2] : 0;
        }
    }

    // per-lane B byte offsets for all 10 k-steps, chunk-XOR swizzled.
    int bofs[10], bofs4[10];
#pragma unroll
    for (int ks = 0; ks < 10; ++ks) {
        int oct = ks * 4 + q;
        int dk = (oct >= 39) ? 3 : (oct >= 26) ? 2 : (oct >= 13) ? 1 : 0;
        int c = oct - 13 * dk;
        int r = n + dk;
        bofs[ks] = (r * RS + ((c ^ (r & 7)) << 3)) * 2;
        int r4 = 64 + n + dk; if (r4 > 69) r4 = 69;   // discarded rows only
        bofs4[ks] = (r4 * RS + ((c ^ (r4 & 7)) << 3)) * 2;
    }

    barrier_lgkm();                                   // s_xidx visible
    short8 svA[5], svB[5];
    issue_stage(svA, s_xidx, embT, tid, bx, 0);

#define PASS12(Ap, SRC, DST, BIAS, R0L, PL, E)                                   \
    if (wv == 0)      ctap<4,3,0,0,false,PL,false,E>(Ap,SRC,DST,nullptr,bofs,bofs4,BIAS,R0L,l0,hps,lane); \
    else if (wv == 1) ctap<4,2,0,3,true, PL,false,E>(Ap,SRC,DST,nullptr,bofs,bofs4,BIAS,R0L,l0,hps,lane); \
    else if (wv == 2) ctap<3,3,4,0,false,PL,false,E>(Ap,SRC,DST,nullptr,bofs,bofs4,BIAS,R0L,l0,hps,lane); \
    else              ctap<3,2,4,3,true, PL,false,E>(Ap,SRC,DST,nullptr,bofs,bofs4,BIAS,R0L,l0,hps,lane);

    for (int it = 0; it < 4; ++it) {
        // write current tile's staged regs; issue next tile's gather early
        if ((it & 1) == 0) {
            write_stage(svA, s_e, tid);
            if (it < 3) issue_stage(svB, s_xidx, embT, tid, bx, it + 1);
        } else {
            write_stage(svB, s_e, tid);
            if (it < 3) issue_stage(svA, s_xidx, embT, tid, bx, it + 1);
        }
        barrier_lgkm();

        const int t = bx * 4 + it;
        const int l0 = t * 64;
        float* hps = hpart + ((b * 16 + t * 2) + (wv & 1)) * 112;
        short* gouts = locT + ((size_t)b * 512 + l0) * 112;
        const bool edge = (t == 0) || (t == 7);

        if (edge) {
            PASS12(A1, s_e, s_h, b1, l0 - 2, true, true)
            barrier_lgkm();
            PASS12(A2, s_h, s_e, b2, l0 - 1, false, true)
        } else {
            PASS12(A1, s_e, s_h, b1, l0 - 2, true, false)
            barrier_lgkm();
            PASS12(A2, s_h, s_e, b2, l0 - 1, false, false)
        }
        barrier_lgkm();
        // li: outputs l in [l0, l0+63] always valid
        if (wv == 0)      ctap<4,2,0,0,false,false,true,false>(A3,s_e,nullptr,gouts,bofs,bofs4,b3,l0,l0,hps,lane);
        else if (wv == 1) ctap<4,2,0,2,false,false,true,false>(A3,s_e,nullptr,gouts,bofs,bofs4,b3,l0,l0,hps,lane);
        else if (wv == 2) ctap<3,2,4,0,false,false,true,false>(A3,s_e,nullptr,gouts,bofs,bofs4,b3,l0,l0,hps,lane);
        else              ctap<3,2,4,2,false,false,true,false>(A3,s_e,nullptr,gouts,bofs,bofs4,b3,l0,l0,hps,lane);
        barrier_lgkm();        // protect s_e before next tile's write_stage
    }
#undef PASS12
}

// ---------------------------------------------------------------------------
// conv3 (1x1, loc half) + conv4 fused -> logits. 128-l tile; balanced:
// wv0=(4mt@0, nt0-3) wv1=(4mt@0, nt4-7) wv2=(3mt@4, nt0-3) wv3=(3mt@4,nt4-7).
// Same chunk-XOR LDS swizzle + contiguous-ks A4 layout.
// LDS 128*RS*2 + 1024 = 33792 B -> 4 blocks/CU.
// ---------------------------------------------------------------------------
template<int MT, int MTB, int NTB, int SLOT>
DEV void c3tile(const short* s_in, float* s_part, const short* __restrict__ A4,
                const float* __restrict__ zg, const float* __restrict__ w4,
                int bb, int lane) {
    const int q = lane >> 4, n = lane & 15;
    const f32x4 z4 = {0.f, 0.f, 0.f, 0.f};
    f32x4 acc[MT][4];
#pragma unroll
    for (int mt = 0; mt < MT; ++mt) {
        int fb = (MTB + mt) * 16 + q * 4;
        f32x4 zgv = *(const f32x4*)&zg[bb * 112 + fb];  // pad entries are 0
#pragma unroll
        for (int nt = 0; nt < 4; ++nt) acc[mt][nt] = zgv;
    }
#pragma unroll
    for (int ks = 0; ks < 4; ++ks) {
        short8 a[MT];
#pragma unroll
        for (int mt = 0; mt < MT; ++mt)
            a[mt] = *(const short8*)&A4[(((MTB + mt) * 64 + lane) * 4 + ks) * 8];
        int cc = ks * 4 + q;
        if (cc > 13) cc = 13;   // A zero for kappa>=100
        const char* bp = (const char*)(s_in + n * RS + ((cc ^ (n & 7)) << 3));
        short8 bf[4];
#pragma unroll
        for (int nt = 0; nt < 4; ++nt)
            bf[nt] = *(const short8*)(bp + (NTB + nt) * ROWB);
#pragma unroll
        for (int mt = 0; mt < MT; ++mt)
#pragma unroll
            for (int nt = 0; nt < 4; ++nt)
                acc[mt][nt] = __builtin_amdgcn_mfma_f32_16x16x32_bf16(
                    a[mt], bf[nt], acc[mt][nt], 0, 0, 0);
    }
#pragma unroll
    for (int nt = 0; nt < 4; ++nt) {
        float part = 0.f;
#pragma unroll
        for (int mt = 0; mt < MT; ++mt) {
            const int fb = (MTB + mt) * 16 + q * 4;
            f32x4 w4v = (fb < 100) ? *(const f32x4*)&w4[fb] : z4;
#pragma unroll
            for (int r = 0; r < 4; ++r)
                part += fmaxf(acc[mt][nt][r], 0.f) * w4v[r];
        }
        part += __shfl_xor(part, 16, 64);
        part += __shfl_xor(part, 32, 64);
        if (q == 0) s_part[SLOT * 128 + (NTB + nt) * 16 + n] = part;
    }
}

__global__ __launch_bounds__(256, 4) void conv3_logits_kernel(
    const short* __restrict__ locT, const short* __restrict__ A4,
    const float* __restrict__ zg, const float* __restrict__ w4,
    const float* __restrict__ b4, float* __restrict__ logits) {
    extern __shared__ char smem[];
    short* s_in = (short*)smem;                     // [128][RS]
    float* s_part = (float*)(smem + 128 * RS * 2);  // [2][128]
    const int tid = threadIdx.x;
    const int b = blockIdx.y, l0r = blockIdx.x * 128;
    const int lane = tid & 63, wv = tid >> 6;

    {
        short8 tmp[8];
#pragma unroll
        for (int p = 0; p < 8; ++p) {
            int idx = tid + p * 256;
            int j = idx >> 4, c8 = idx & 15;
            if (c8 < 14)
                tmp[p] = *(const short8*)&locT[((size_t)b * 512 + l0r + j) * 112 + c8 * 8];
        }
#pragma unroll
        for (int p = 0; p < 8; ++p) {
            int idx = tid + p * 256;
            int j = idx >> 4, c8 = idx & 15;
            if (c8 < 14)
                *(short8*)&s_in[j * RS + ((c8 ^ (j & 7)) << 3)] = tmp[p];
        }
    }
    __syncthreads();
    if (wv == 0)      c3tile<4, 0, 0, 0>(s_in, s_part, A4, zg, w4, b, lane);
    else if (wv == 1) c3tile<4, 0, 4, 0>(s_in, s_part, A4, zg, w4, b, lane);
    else if (wv == 2) c3tile<3, 4, 0, 1>(s_in, s_part, A4, zg, w4, b, lane);
    else              c3tile<3, 4, 4, 1>(s_in, s_part, A4, zg, w4, b, lane);
    __syncthreads();
    if (tid < 128)
        logits[b * 512 + l0r + tid] = s_part[tid] + s_part[128 + tid] + b4[0];
}

// ---------------------------------------------------------------------------
// Finish pool: hm = sum over 16 wave-slot partials / 512, gate MLP, fold g:
// zg[b,f] = conv3_b[f] + sum_h g[b,h] * w3[f][h]   (f>=100 -> 0)
// ---------------------------------------------------------------------------
__global__ __launch_bounds__(128) void pool_gate_kernel(
    const float* __restrict__ hpart, const float* __restrict__ gi_w,
    const float* __restrict__ gi_b, const float* __restrict__ w3,
    const float* __restrict__ b3, float* __restrict__ zg) {
    int b = blockIdx.x, tid = threadIdx.x;
    __shared__ float s_hm[112];
    __shared__ float s_g[100];
    if (tid < 112) {
        float a = 0.f;
#pragma unroll
        for (int s = 0; s < 16; ++s) a += hpart[(b * 16 + s) * 112 + tid];
        s_hm[tid] = a * (1.f / 512.f);
    }
    __syncthreads();
    if (tid < 100) {
        float a = gi_b[tid];
        for (int f = 0; f < 100; ++f) a += s_hm[f] * gi_w[tid * 100 + f];
        s_g[tid] = fmaxf(a, 0.f);
    }
    __syncthreads();
    if (tid < 112) {
        float a = 0.f;
        if (tid < 100) {
            a = b3[tid];
            for (int h = 0; h < 100; ++h) a += s_g[h] * w3[tid * 200 + h];
        }
        zg[b * 112 + tid] = a;
    }
}

// ---------------------------------------------------------------------------
// Fused sampler + distil head, one block per b. Wave-parallel over k:
// wave wv handles k = wv, wv+4, wv+8 (<10) with wave-local shuffle softmax
// (no barriers inside the k loop). Merge via LDS max, then pooled gather
// (bf16 embT), fc1 relu, sigmoid head.
// ---------------------------------------------------------------------------
__global__ __launch_bounds__(256) void samp_head_kernel(
    const float* __restrict__ u, const float* __restrict__ logits,
    const int* __restrict__ xidx, const short* __restrict__ embT,
    const float* __restrict__ f1w, const float* __restrict__ f1b,
    const float* __restrict__ hw, const float* __restrict__ hb,
    float* __restrict__ cs_out, float* __restrict__ out) {
    const float EPSV = 1.1920929e-07f;
    const float INVT = 1.f / 0.3f;
    int b = blockIdx.x, tid = threadIdx.x;
    int lane = tid & 63, wv = tid >> 6;
    __shared__ float s_logT[512], s_cs[512];
    __shared__ int s_x[512];
    __shared__ float s_csw[4][512];
    __shared__ float s_acc[16][112];
    __shared__ float s_pool[112], s_h2[100], s_fin[4];
    for (int l = tid; l < 512; l += 256) {
        s_logT[l] = logits[b * 512 + l] * INVT;
        s_x[l] = xidx[b * 512 + l];
    }
    __syncthreads();
    // wave-local softmax per k
    const int nk = (wv < 2) ? 3 : 2;
    float csl[8];
#pragma unroll
    for (int i = 0; i < 8; ++i) csl[i] = 0.f;
    float lt[8];
#pragma unroll
    for (int i = 0; i < 8; ++i) lt[i] = s_logT[lane * 8 + i];
    for (int j = 0; j < nk; ++j) {
        int k = wv + 4 * j;
        f32x4 u0 = *(const f32x4*)&u[(b * 10 + k) * 512 + lane * 8];
        f32x4 u1 = *(const f32x4*)&u[(b * 10 + k) * 512 + lane * 8 + 4];
        float nz[8];
#pragma unroll
        for (int i = 0; i < 8; ++i) {
            float vv = (i < 4) ? u0[i] : u1[i - 4];
            vv = fminf(fmaxf(vv, EPSV), 1.f - EPSV);
            nz[i] = -__logf(-__logf(vv)) * INVT + lt[i];
        }
        float m = nz[0];
#pragma unroll
        for (int i = 1; i < 8; ++i) m = fmaxf(m, nz[i]);
#pragma unroll
        for (int off = 1; off <= 32; off <<= 1) m = fmaxf(m, __shfl_xor(m, off, 64));
        float e[8], s = 0.f;
#pragma unroll
        for (int i = 0; i < 8; ++i) { e[i] = __expf(nz[i] - m); s += e[i]; }
#pragma unroll
        for (int off = 1; off <= 32; off <<= 1) s += __shfl_xor(s, off, 64);
        float inv = 1.f / s;
#pragma unroll
        for (int i = 0; i < 8; ++i) csl[i] = fmaxf(csl[i], e[i] * inv);
    }
#pragma unroll
    for (int i = 0; i < 8; ++i) s_csw[wv][lane * 8 + i] = csl[i];
    __syncthreads();
    for (int l = tid; l < 512; l += 256) {
        float c = fmaxf(fmaxf(s_csw[0][l], s_csw[1][l]),
                        fmaxf(s_csw[2][l], s_csw[3][l]));
        s_cs[l] = c;
        cs_out[b * 512 + l] = c;
    }
    __syncthreads();
    // pooled partial sums: thread (jg, c8) covers l = jg+16t, channels c8*8..+7
    int jg = tid >> 4, c8 = tid & 15;
    if (c8 < 14) {
        f32x4 pa = {0.f, 0.f, 0.f, 0.f}, pb = {0.f, 0.f, 0.f, 0.f};
#pragma unroll 4
        for (int l = jg; l < 512; l += 16) {
            int row = s_x[l];
            float cv = s_cs[l];
            short8 e8 = *(const short8*)&embT[(size_t)row * 112 + c8 * 8];
#pragma unroll
            for (int r = 0; r < 4; ++r) {
                pa[r] += cv * bfu(e8[r]);
                pb[r] += cv * bfu(e8[4 + r]);
            }
        }
        *(f32x4*)&s_acc[jg][c8 * 8] = pa;
        *(f32x4*)&s_acc[jg][c8 * 8 + 4] = pb;
    }
    __syncthreads();
    if (tid < 112) {
        float p = 0.f;
#pragma unroll
        for (int g = 0; g < 16; ++g) p += s_acc[g][tid];
        s_pool[tid] = p * (1.f / 512.f);
    }
    __syncthreads();
    if (tid < 100) {
        float a = f1b[tid];
        for (int i = 0; i < 100; ++i) a += s_pool[i] * f1w[tid * 100 + i];
        s_h2[tid] = fmaxf(a, 0.f);
    }
    __syncthreads();
    float v = (tid < 100) ? s_h2[tid] * hw[tid] : 0.f;
#pragma unroll
    for (int off = 32; off >= 1; off >>= 1) v += __shfl_xor(v, off, 64);
    if (lane == 0) s_fin[wv] = v;
    __syncthreads();
    if (tid == 0) {
        float z = s_fin[0] + s_fin[1] + s_fin[2] + s_fin[3] + hb[0];
        out[b] = 1.f / (1.f + __expf(-z));
    }
}

// ---------------------------------------------------------------------------
extern "C" void kernel_launch(void* const* d_in, const int* in_sizes, int n_in,
                              void* d_out, int out_size, void* d_ws, size_t ws_size,
                              hipStream_t stream) {
    const int*   x   = (const int*)d_in[0];
    const float* u   = (const float*)d_in[1];
    const float* emb = (const float*)d_in[2];
    const float* c1w = (const float*)d_in[3];
    const float* c1b = (const float*)d_in[4];
    const float* giw = (const float*)d_in[5];
    const float* gib = (const float*)d_in[6];
    const float* c2w = (const float*)d_in[7];
    const float* c2b = (const float*)d_in[8];
    const float* liw = (const float*)d_in[9];
    const float* lib = (const float*)d_in[10];
    const float* c3w = (const float*)d_in[11];
    const float* c3b = (const float*)d_in[12];
    const float* c4w = (const float*)d_in[13];
    const float* c4b = (const float*)d_in[14];
    const float* f1w = (const float*)d_in[15];
    const float* f1b = (const float*)d_in[16];
    const float* hww = (const float*)d_in[17];
    const float* hbb = (const float*)d_in[18];
    float* out = (float*)d_out;

    char* ws = (char*)d_ws;
    short* locT   = (short*)(ws + 0);           // [512][512][112] bf16 (58.7 MB)
    short* embT   = (short*)(ws + 58720256);    // [100000][112] bf16 (22.4 MB)
    short* A1     = (short*)(ws + 81120256);    // 10*448*16 B each
    short* A2     = (short*)(ws + 81191936);
    short* A3     = (short*)(ws + 81263616);
    short* A4     = (short*)(ws + 81335296);    // 4*448*16 B
    float* zg     = (float*)(ws + 81363968);    // [512][112]
    float* logits = (float*)(ws + 81593344);    // [512][512]
    float* hpart  = (float*)(ws + 82641920);    // [512][8][2][112]

    emb_cvt_kernel<<<12500, 256, 0, stream>>>(emb, embT);
    pack_all_kernel<<<238, 64, 0, stream>>>(c1w, c2w, liw, c3w, A1, A2, A3, A4);

    size_t smemA = (size_t)2 * 72 * RS * 2 + 264 * 4;  // 37920 B -> 4 blocks/CU
    fused_conv_kernel<<<dim3(2, 512), 256, smemA, stream>>>(
        x, embT, A1, A2, A3, c1b, c2b, lib, locT, hpart);
    pool_gate_kernel<<<512, 128, 0, stream>>>(hpart, giw, gib, c3w, c3b, zg);
    size_t smemB = (size_t)128 * RS * 2 + 2 * 128 * 4; // 33792 B -> 4 blocks/CU
    conv3_logits_kernel<<<dim3(4, 512), 256, smemB, stream>>>(
        locT, A4, zg, c4w, c4b, logits);
    samp_head_kernel<<<512, 256, 0, stream>>>(
        u, logits, x, embT, f1w, f1b, hww, hbb, out + 512, out);
}

// Round 2
// 561.350 us; speedup vs baseline: 1.8127x; 1.8127x over previous
//
#include <hip/hip_runtime.h>
#include <math.h>

#define DEV __device__ __forceinline__

typedef __attribute__((ext_vector_type(8))) short short8;
typedef __attribute__((ext_vector_type(4))) short short4v;
typedef __attribute__((ext_vector_type(4))) float f32x4;
typedef __attribute__((ext_vector_type(2))) unsigned uint2v;

// LDS rows: 128 shorts (256 B = 16 chunks of 16 B), linear (no pad) so
// global_load_lds can write them directly (wave-uniform base + lane*16).
// Bank spread handled by XOR-swizzling the 16B-chunk index with (row & 7):
// the swizzle lives in the per-lane GLOBAL source address on the write side
// (rule #21: linear dest + pre-swizzled source) and in bofs on the read side.
#define RS 128
#define ROWB (16 * RS * 2)   // 4096 B per 16-row tile

DEV short f2bf(float f) {
    unsigned u = __builtin_bit_cast(unsigned, f);
    unsigned r = (u + 0x7fffu + ((u >> 16) & 1u)) >> 16;
    return (short)r;
}

#if __has_builtin(__builtin_amdgcn_cvt_pk_bf16_f32)
DEV unsigned pk2bf(float a, float b) {
    auto v = __builtin_amdgcn_cvt_pk_bf16_f32(a, b);
    return __builtin_bit_cast(unsigned, v);
}
#else
DEV unsigned pk2bf(float a, float b) {
    return ((unsigned)(unsigned short)f2bf(a)) |
           (((unsigned)(unsigned short)f2bf(b)) << 16);
}
#endif

DEV float bfu(short s) {
    unsigned u = ((unsigned)(unsigned short)s) << 16;
    return __builtin_bit_cast(float, u);
}

// Direct global->LDS 16B DMA. LDS dest must be wave-uniform; HW adds lane*16.
DEV void gl_lds16(const void* gsrc, void* ldst) {
    __builtin_amdgcn_global_load_lds(
        (const __attribute__((address_space(1))) void*)gsrc,
        (__attribute__((address_space(3))) void*)ldst, 16, 0, 0);
}

// ---------------------------------------------------------------------------
// emb f32 [V][100] -> bf16 [V][112], cols 100..111 zeroed. 8 rows/block.
// ---------------------------------------------------------------------------
__global__ __launch_bounds__(256) void emb_cvt_kernel(
    const float* __restrict__ emb, short* __restrict__ embT) {
    int t = threadIdx.x;
    int row = blockIdx.x * 8 + (t >> 5);
    int c4 = t & 31;
    if (c4 >= 28) return;
    short4v v = {0, 0, 0, 0};
    if (c4 < 25) {
        f32x4 e = *(const f32x4*)&emb[row * 100 + c4 * 4];
#pragma unroll
        for (int r = 0; r < 4; ++r) v[r] = f2bf(e[r]);
    }
    *(short4v*)&embT[row * 112 + c4 * 4] = v;
}

// ---------------------------------------------------------------------------
// Pack conv weights into MFMA A-fragment order.
// Layout: [fblk*64 + lane][ks] contiguous in ks -> K-loop A-loads are ONE
// base address per mt + imm offsets ks*16B (0..144).
// mode 0 (3-tap): 13 octets per tap; K = 320 (10 ks).
// mode 1 (conv3 loc half): kappa = c (cols 100..199 of w[100][200]), K 128.
// ---------------------------------------------------------------------------
__global__ __launch_bounds__(64) void pack_all_kernel(
    const float* __restrict__ c1w, const float* __restrict__ c2w,
    const float* __restrict__ liw, const float* __restrict__ c3w,
    short* __restrict__ A1, short* __restrict__ A2,
    short* __restrict__ A3, short* __restrict__ A4) {
    int bx = blockIdx.x;
    const float* w; short* dst; int mode, lbx;
    if (bx < 70)       { w = c1w; dst = A1; mode = 0; lbx = bx; }
    else if (bx < 140) { w = c2w; dst = A2; mode = 0; lbx = bx - 70; }
    else if (bx < 210) { w = liw; dst = A3; mode = 0; lbx = bx - 140; }
    else               { w = c3w; dst = A4; mode = 1; lbx = bx - 210; }
    int lane = threadIdx.x;
    int fblk = lbx % 7, ksb = lbx / 7;
    int f = fblk * 16 + (lane & 15);
    int kb = ksb * 32 + (lane >> 4) * 8;
    int nks = (mode == 0) ? 10 : 4;
    short8 v;
#pragma unroll
    for (int j = 0; j < 8; ++j) {
        int kk = kb + j;
        float val = 0.f;
        if (f < 100) {
            if (mode == 0) {
                int oct = kk >> 3, dk = oct / 13;
                int c = (oct - 13 * dk) * 8 + (kk & 7);
                if (dk < 3 && c < 100) val = w[(f * 100 + c) * 3 + dk];
            } else {
                if (kk < 100) val = w[f * 200 + 100 + kk];
            }
        }
        v[j] = f2bf(val);
    }
    *(short8*)&dst[((fblk * 64 + lane) * nks + ksb) * 8] = v;
}

// ---------------------------------------------------------------------------
// One 3-tap conv pass, BALANCED tile: this wave owns mt [MTB,MTB+MT) x
// nt [NTB,NTB+NT). Accumulator init = bias. CLAMPL: the nt==4 tile reads
// clamped rows (feeds only discarded outputs). EDGE: l-range zeroing only in
// edge tiles. POOL: relu partial sums for l in [l0,l0+64) -> hpart_slot[112].
// bofs[] carry the chunk XOR swizzle (key = row&7; 16*nt offset doesn't
// affect row&7, so one bofs serves all nt).
// ---------------------------------------------------------------------------
template<int MT, int NT, int MTB, int NTB, bool CLAMPL, bool POOL,
         bool TO_GLOBAL, bool EDGE>
DEV void ctap(const short* __restrict__ Ap, const short* s_src, short* s_dst,
              short* __restrict__ gout, const int* bofs, const int* bofs4,
              const float* __restrict__ bias, int row0l, int l0,
              float* __restrict__ hpart_slot, int lane) {
    const int q = lane >> 4, n = lane & 15;
    const int skey = n & 7;
    const f32x4 z4 = {0.f, 0.f, 0.f, 0.f};
    f32x4 acc[MT][NT];
#pragma unroll
    for (int mt = 0; mt < MT; ++mt) {
        int fb = (MTB + mt) * 16 + q * 4;
        f32x4 bs = (fb < 100) ? *(const f32x4*)&bias[fb] : z4;
#pragma unroll
        for (int nt = 0; nt < NT; ++nt) acc[mt][nt] = bs;
    }
#pragma unroll
    for (int ks = 0; ks < 10; ++ks) {
        short8 a[MT];
#pragma unroll
        for (int mt = 0; mt < MT; ++mt)
            a[mt] = *(const short8*)&Ap[(((MTB + mt) * 64 + lane) * 10 + ks) * 8];
        const char* bp = (const char*)s_src + bofs[ks];
        short8 bf[NT];
#pragma unroll
        for (int nt = 0; nt < NT; ++nt) {
            if (CLAMPL && (NTB + nt) == 4)
                bf[nt] = *(const short8*)((const char*)s_src + bofs4[ks]);
            else
                bf[nt] = *(const short8*)(bp + (NTB + nt) * ROWB);
        }
#pragma unroll
        for (int mt = 0; mt < MT; ++mt)
#pragma unroll
            for (int nt = 0; nt < NT; ++nt)
                acc[mt][nt] = __builtin_amdgcn_mfma_f32_16x16x32_bf16(
                    a[mt], bf[nt], acc[mt][nt], 0, 0, 0);
    }
    f32x4 ps[MT];
    if constexpr (POOL) {
#pragma unroll
        for (int mt = 0; mt < MT; ++mt) ps[mt] = z4;
    }
#pragma unroll
    for (int nt = 0; nt < NT; ++nt) {
        const int j = (NTB + nt) * 16 + n;
        const int l = row0l + j;
        bool lok = true;
        if constexpr (EDGE) lok = ((unsigned)l < 512u);
        const bool pok = POOL && (l >= l0) && (l < l0 + 64);
#pragma unroll
        for (int mt = 0; mt < MT; ++mt) {
            const int fb = (MTB + mt) * 16 + q * 4;
            f32x4 v;
#pragma unroll
            for (int r = 0; r < 4; ++r) {
                v[r] = fmaxf(acc[mt][nt][r], 0.f);
                if constexpr (EDGE) v[r] = lok ? v[r] : 0.f;
            }
            if constexpr (POOL) {
                if (pok) {
#pragma unroll
                    for (int r = 0; r < 4; ++r) ps[mt][r] += v[r];
                }
            }
            uint2v pk;
            pk[0] = pk2bf(v[0], v[1]); pk[1] = pk2bf(v[2], v[3]);
            if constexpr (TO_GLOBAL) {
                *(uint2v*)&gout[j * 112 + fb] = pk;
            } else {
                if ((NTB + nt) < 4 || n < 6) {    // store rows j < 70 only
                    const int cch = (MTB + mt) * 2 + (q >> 1);
                    *(uint2v*)&s_dst[j * RS + ((cch ^ skey) << 3) + (q & 1) * 4] = pk;
                }
            }
        }
    }
    if constexpr (POOL) {
#pragma unroll
        for (int mt = 0; mt < MT; ++mt)
#pragma unroll
            for (int off = 1; off <= 8; off <<= 1)
#pragma unroll
                for (int r = 0; r < 4; ++r)
                    ps[mt][r] += __shfl_xor(ps[mt][r], off, 64);
        if (n == 0) {
#pragma unroll
            for (int mt = 0; mt < MT; ++mt)
                *(f32x4*)&hpart_slot[(MTB + mt) * 16 + q * 4] = ps[mt];
        }
    }
}

// ---------------------------------------------------------------------------
// Fused conv1 -> conv2 -> li, 64-wide l-tile, 256 threads (4 waves), grid
// (8,512) -- the proven r0 structure. Staging of the 70 e-rows goes straight
// global->LDS via global_load_lds (no VGPR round-trip, no ds_writes):
// every issue is full-wave (guards are wave-uniform); per-lane OOB xidx
// indices are clamped (garbage rows 70/71 never read; edge-halo rows are
// explicitly zeroed after the staging barrier).
// LDS 2*72*RS*2 = 36864 B -> 4 blocks/CU.
// ---------------------------------------------------------------------------
__global__ __launch_bounds__(256, 4) void fused_conv_kernel(
    const int* __restrict__ xidx, const short* __restrict__ embT,
    const short* __restrict__ A1, const short* __restrict__ A2,
    const short* __restrict__ A3,
    const float* __restrict__ b1, const float* __restrict__ b2,
    const float* __restrict__ b3,
    short* __restrict__ locT, float* __restrict__ hpart) {
    extern __shared__ char smem[];
    short* s_e = (short*)smem;                        // [72][RS], later c2
    short* s_h = (short*)(smem + 72 * RS * 2);        // [72][RS]
    const int tid = threadIdx.x;
    const int b = blockIdx.y, bx = blockIdx.x, l0 = bx * 64;
    const int lane = tid & 63, wv = tid >> 6;
    const int q = lane >> 4, n = lane & 15;

    // --- stage e rows 0..71: linear LDS dest + pre-swizzled global source ---
    {
        const int jr = tid >> 4;               // wv*4 + (lane>>4): row at p=0
        const int g = (tid & 15) ^ (jr & 7);   // logical chunk this lane loads
        int rows[5];
#pragma unroll
        for (int p = 0; p < 5; ++p) {
            int lg = l0 - 3 + jr + p * 16;
            int lgc = lg < 0 ? 0 : (lg > 511 ? 511 : lg);
            rows[p] = xidx[b * 512 + lgc];
        }
#pragma unroll
        for (int p = 0; p < 5; ++p) {
            if (wv * 4 + p * 16 < 72)          // wave-uniform guard, full exec
                gl_lds16(&embT[(size_t)rows[p] * 112 + g * 8],
                         &s_e[(wv * 4 + p * 16) * RS]);
        }
    }

    // per-lane B byte offsets for all 10 k-steps, chunk-XOR swizzled.
    int bofs[10], bofs4[10];
#pragma unroll
    for (int ks = 0; ks < 10; ++ks) {
        int oct = ks * 4 + q;
        int dk = (oct >= 39) ? 3 : (oct >= 26) ? 2 : (oct >= 13) ? 1 : 0;
        int c = oct - 13 * dk;
        int r = n + dk;
        bofs[ks] = (r * RS + ((c ^ (r & 7)) << 3)) * 2;
        int r4 = 64 + n + dk; if (r4 > 69) r4 = 69;   // discarded rows only
        bofs4[ks] = (r4 * RS + ((c ^ (r4 & 7)) << 3)) * 2;
    }
    float* hps = hpart + ((b * 8 + bx) * 2 + (wv & 1)) * 112;
    short* gouts = locT + ((size_t)b * 512 + l0) * 112;

    __syncthreads();                                  // drains vmcnt: loads landed
    const bool edge = (bx == 0) || (bx == 7);
    if (edge) {                                       // zero the halo rows
        if (tid < 48) {
            int row = (bx == 0 ? 0 : 67) + (tid >> 4);
            short8 z = {0, 0, 0, 0, 0, 0, 0, 0};
            *(short8*)&s_e[row * RS + (tid & 15) * 8] = z;
        }
        __syncthreads();
    }

#define PASS3T(Ap, SRC, DST, BIAS, R0L, PL, E)                                   \
    if (wv == 0)      ctap<4,3,0,0,false,PL,false,E>(Ap,SRC,DST,nullptr,bofs,bofs4,BIAS,R0L,l0,hps,lane); \
    else if (wv == 1) ctap<4,2,0,3,true, PL,false,E>(Ap,SRC,DST,nullptr,bofs,bofs4,BIAS,R0L,l0,hps,lane); \
    else if (wv == 2) ctap<3,3,4,0,false,PL,false,E>(Ap,SRC,DST,nullptr,bofs,bofs4,BIAS,R0L,l0,hps,lane); \
    else              ctap<3,2,4,3,true, PL,false,E>(Ap,SRC,DST,nullptr,bofs,bofs4,BIAS,R0L,l0,hps,lane);

    if (edge) {
        PASS3T(A1, s_e, s_h, b1, l0 - 2, true, true)
        __syncthreads();
        PASS3T(A2, s_h, s_e, b2, l0 - 1, false, true)
    } else {
        PASS3T(A1, s_e, s_h, b1, l0 - 2, true, false)
        __syncthreads();
        PASS3T(A2, s_h, s_e, b2, l0 - 1, false, false)
    }
    __syncthreads();
    // li: outputs l in [l0, l0+63] always valid
    if (wv == 0)      ctap<4,2,0,0,false,false,true,false>(A3,s_e,nullptr,gouts,bofs,bofs4,b3,l0,l0,hps,lane);
    else if (wv == 1) ctap<4,2,0,2,false,false,true,false>(A3,s_e,nullptr,gouts,bofs,bofs4,b3,l0,l0,hps,lane);
    else if (wv == 2) ctap<3,2,4,0,false,false,true,false>(A3,s_e,nullptr,gouts,bofs,bofs4,b3,l0,l0,hps,lane);
    else              ctap<3,2,4,2,false,false,true,false>(A3,s_e,nullptr,gouts,bofs,bofs4,b3,l0,l0,hps,lane);
#undef PASS3T
}

// ---------------------------------------------------------------------------
// conv3 (1x1, loc half) + conv4 fused -> logits. 128-l tile; balanced:
// wv0=(4mt@0, nt0-3) wv1=(4mt@0, nt4-7) wv2=(3mt@4, nt0-3) wv3=(3mt@4,nt4-7).
// Staging via global_load_lds (no tail: 128 rows x 16 chunks = 8 full-wave
// issues per wave). Same chunk-XOR swizzle + contiguous-ks A4 layout.
// LDS 128*RS*2 + 1024 = 66560... see launch: 128*RS*2 = 65536 + 1024.
// ---------------------------------------------------------------------------
template<int MT, int MTB, int NTB, int SLOT>
DEV void c3tile(const short* s_in, float* s_part, const short* __restrict__ A4,
                const float* __restrict__ zg, const float* __restrict__ w4,
                int bb, int lane) {
    const int q = lane >> 4, n = lane & 15;
    const f32x4 z4 = {0.f, 0.f, 0.f, 0.f};
    f32x4 acc[MT][4];
#pragma unroll
    for (int mt = 0; mt < MT; ++mt) {
        int fb = (MTB + mt) * 16 + q * 4;
        f32x4 zgv = *(const f32x4*)&zg[bb * 112 + fb];  // pad entries are 0
#pragma unroll
        for (int nt = 0; nt < 4; ++nt) acc[mt][nt] = zgv;
    }
#pragma unroll
    for (int ks = 0; ks < 4; ++ks) {
        short8 a[MT];
#pragma unroll
        for (int mt = 0; mt < MT; ++mt)
            a[mt] = *(const short8*)&A4[(((MTB + mt) * 64 + lane) * 4 + ks) * 8];
        int cc = ks * 4 + q;
        if (cc > 13) cc = 13;   // A zero for kappa>=100; chunk 13 = zeros
        const char* bp = (const char*)(s_in + n * RS + ((cc ^ (n & 7)) << 3));
        short8 bf[4];
#pragma unroll
        for (int nt = 0; nt < 4; ++nt)
            bf[nt] = *(const short8*)(bp + (NTB + nt) * ROWB);
#pragma unroll
        for (int mt = 0; mt < MT; ++mt)
#pragma unroll
            for (int nt = 0; nt < 4; ++nt)
                acc[mt][nt] = __builtin_amdgcn_mfma_f32_16x16x32_bf16(
                    a[mt], bf[nt], acc[mt][nt], 0, 0, 0);
    }
#pragma unroll
    for (int nt = 0; nt < 4; ++nt) {
        float part = 0.f;
#pragma unroll
        for (int mt = 0; mt < MT; ++mt) {
            const int fb = (MTB + mt) * 16 + q * 4;
            f32x4 w4v = (fb < 100) ? *(const f32x4*)&w4[fb] : z4;
#pragma unroll
            for (int r = 0; r < 4; ++r)
                part += fmaxf(acc[mt][nt][r], 0.f) * w4v[r];
        }
        part += __shfl_xor(part, 16, 64);
        part += __shfl_xor(part, 32, 64);
        if (q == 0) s_part[SLOT * 128 + (NTB + nt) * 16 + n] = part;
    }
}

__global__ __launch_bounds__(256, 2) void conv3_logits_kernel(
    const short* __restrict__ locT, const short* __restrict__ A4,
    const float* __restrict__ zg, const float* __restrict__ w4,
    const float* __restrict__ b4, float* __restrict__ logits) {
    extern __shared__ char smem[];
    short* s_in = (short*)smem;                     // [128][RS]
    float* s_part = (float*)(smem + 128 * RS * 2);  // [2][128]
    const int tid = threadIdx.x;
    const int b = blockIdx.y, l0r = blockIdx.x * 128;
    const int lane = tid & 63, wv = tid >> 6;

    {
        const int jr = tid >> 4;
        const int g = (tid & 15) ^ (jr & 7);
        const size_t rowbase = (size_t)b * 512 + l0r;
#pragma unroll
        for (int p = 0; p < 8; ++p) {
            int j = jr + p * 16;
            gl_lds16(&locT[(rowbase + j) * 112 + g * 8],
                     &s_in[(wv * 4 + p * 16) * RS]);
        }
    }
    __syncthreads();
    if (wv == 0)      c3tile<4, 0, 0, 0>(s_in, s_part, A4, zg, w4, b, lane);
    else if (wv == 1) c3tile<4, 0, 4, 0>(s_in, s_part, A4, zg, w4, b, lane);
    else if (wv == 2) c3tile<3, 4, 0, 1>(s_in, s_part, A4, zg, w4, b, lane);
    else              c3tile<3, 4, 4, 1>(s_in, s_part, A4, zg, w4, b, lane);
    __syncthreads();
    if (tid < 128)
        logits[b * 512 + l0r + tid] = s_part[tid] + s_part[128 + tid] + b4[0];
}

// ---------------------------------------------------------------------------
// Finish pool: hm = sum over 16 wave-slot partials / 512, gate MLP, fold g:
// zg[b,f] = conv3_b[f] + sum_h g[b,h] * w3[f][h]   (f>=100 -> 0)
// ---------------------------------------------------------------------------
__global__ __launch_bounds__(128) void pool_gate_kernel(
    const float* __restrict__ hpart, const float* __restrict__ gi_w,
    const float* __restrict__ gi_b, const float* __restrict__ w3,
    const float* __restrict__ b3, float* __restrict__ zg) {
    int b = blockIdx.x, tid = threadIdx.x;
    __shared__ float s_hm[112];
    __shared__ float s_g[100];
    if (tid < 112) {
        float a = 0.f;
#pragma unroll
        for (int s = 0; s < 16; ++s) a += hpart[(b * 16 + s) * 112 + tid];
        s_hm[tid] = a * (1.f / 512.f);
    }
    __syncthreads();
    if (tid < 100) {
        float a = gi_b[tid];
        for (int f = 0; f < 100; ++f) a += s_hm[f] * gi_w[tid * 100 + f];
        s_g[tid] = fmaxf(a, 0.f);
    }
    __syncthreads();
    if (tid < 112) {
        float a = 0.f;
        if (tid < 100) {
            a = b3[tid];
            for (int h = 0; h < 100; ++h) a += s_g[h] * w3[tid * 200 + h];
        }
        zg[b * 112 + tid] = a;
    }
}

// ---------------------------------------------------------------------------
// Fused sampler + distil head, one block per b. Wave-parallel over k:
// wave wv handles k = wv, wv+4, wv+8 (<10) with wave-local shuffle softmax
// (no barriers inside the k loop). Merge via LDS max, then pooled gather
// (bf16 embT), fc1 relu, sigmoid head.
// ---------------------------------------------------------------------------
__global__ __launch_bounds__(256) void samp_head_kernel(
    const float* __restrict__ u, const float* __restrict__ logits,
    const int* __restrict__ xidx, const short* __restrict__ embT,
    const float* __restrict__ f1w, const float* __restrict__ f1b,
    const float* __restrict__ hw, const float* __restrict__ hb,
    float* __restrict__ cs_out, float* __restrict__ out) {
    const float EPSV = 1.1920929e-07f;
    const float INVT = 1.f / 0.3f;
    int b = blockIdx.x, tid = threadIdx.x;
    int lane = tid & 63, wv = tid >> 6;
    __shared__ float s_logT[512], s_cs[512];
    __shared__ int s_x[512];
    __shared__ float s_csw[4][512];
    __shared__ float s_acc[16][112];
    __shared__ float s_pool[112], s_h2[100], s_fin[4];
    for (int l = tid; l < 512; l += 256) {
        s_logT[l] = logits[b * 512 + l] * INVT;
        s_x[l] = xidx[b * 512 + l];
    }
    __syncthreads();
    // wave-local softmax per k
    const int nk = (wv < 2) ? 3 : 2;
    float csl[8];
#pragma unroll
    for (int i = 0; i < 8; ++i) csl[i] = 0.f;
    float lt[8];
#pragma unroll
    for (int i = 0; i < 8; ++i) lt[i] = s_logT[lane * 8 + i];
    for (int j = 0; j < nk; ++j) {
        int k = wv + 4 * j;
        f32x4 u0 = *(const f32x4*)&u[(b * 10 + k) * 512 + lane * 8];
        f32x4 u1 = *(const f32x4*)&u[(b * 10 + k) * 512 + lane * 8 + 4];
        float nz[8];
#pragma unroll
        for (int i = 0; i < 8; ++i) {
            float vv = (i < 4) ? u0[i] : u1[i - 4];
            vv = fminf(fmaxf(vv, EPSV), 1.f - EPSV);
            nz[i] = -__logf(-__logf(vv)) * INVT + lt[i];
        }
        float m = nz[0];
#pragma unroll
        for (int i = 1; i < 8; ++i) m = fmaxf(m, nz[i]);
#pragma unroll
        for (int off = 1; off <= 32; off <<= 1) m = fmaxf(m, __shfl_xor(m, off, 64));
        float e[8], s = 0.f;
#pragma unroll
        for (int i = 0; i < 8; ++i) { e[i] = __expf(nz[i] - m); s += e[i]; }
#pragma unroll
        for (int off = 1; off <= 32; off <<= 1) s += __shfl_xor(s, off, 64);
        float inv = 1.f / s;
#pragma unroll
        for (int i = 0; i < 8; ++i) csl[i] = fmaxf(csl[i], e[i] * inv);
    }
#pragma unroll
    for (int i = 0; i < 8; ++i) s_csw[wv][lane * 8 + i] = csl[i];
    __syncthreads();
    for (int l = tid; l < 512; l += 256) {
        float c = fmaxf(fmaxf(s_csw[0][l], s_csw[1][l]),
                        fmaxf(s_csw[2][l], s_csw[3][l]));
        s_cs[l] = c;
        cs_out[b * 512 + l] = c;
    }
    __syncthreads();
    // pooled partial sums: thread (jg, c8) covers l = jg+16t, channels c8*8..+7
    int jg = tid >> 4, c8 = tid & 15;
    if (c8 < 14) {
        f32x4 pa = {0.f, 0.f, 0.f, 0.f}, pb = {0.f, 0.f, 0.f, 0.f};
#pragma unroll 4
        for (int l = jg; l < 512; l += 16) {
            int row = s_x[l];
            float cv = s_cs[l];
            short8 e8 = *(const short8*)&embT[(size_t)row * 112 + c8 * 8];
#pragma unroll
            for (int r = 0; r < 4; ++r) {
                pa[r] += cv * bfu(e8[r]);
                pb[r] += cv * bfu(e8[4 + r]);
            }
        }
        *(f32x4*)&s_acc[jg][c8 * 8] = pa;
        *(f32x4*)&s_acc[jg][c8 * 8 + 4] = pb;
    }
    __syncthreads();
    if (tid < 112) {
        float p = 0.f;
#pragma unroll
        for (int g = 0; g < 16; ++g) p += s_acc[g][tid];
        s_pool[tid] = p * (1.f / 512.f);
    }
    __syncthreads();
    if (tid < 100) {
        float a = f1b[tid];
        for (int i = 0; i < 100; ++i) a += s_pool[i] * f1w[tid * 100 + i];
        s_h2[tid] = fmaxf(a, 0.f);
    }
    __syncthreads();
    float v = (tid < 100) ? s_h2[tid] * hw[tid] : 0.f;
#pragma unroll
    for (int off = 32; off >= 1; off >>= 1) v += __shfl_xor(v, off, 64);
    if (lane == 0) s_fin[wv] = v;
    __syncthreads();
    if (tid == 0) {
        float z = s_fin[0] + s_fin[1] + s_fin[2] + s_fin[3] + hb[0];
        out[b] = 1.f / (1.f + __expf(-z));
    }
}

// ---------------------------------------------------------------------------
extern "C" void kernel_launch(void* const* d_in, const int* in_sizes, int n_in,
                              void* d_out, int out_size, void* d_ws, size_t ws_size,
                              hipStream_t stream) {
    const int*   x   = (const int*)d_in[0];
    const float* u   = (const float*)d_in[1];
    const float* emb = (const float*)d_in[2];
    const float* c1w = (const float*)d_in[3];
    const float* c1b = (const float*)d_in[4];
    const float* giw = (const float*)d_in[5];
    const float* gib = (const float*)d_in[6];
    const float* c2w = (const float*)d_in[7];
    const float* c2b = (const float*)d_in[8];
    const float* liw = (const float*)d_in[9];
    const float* lib = (const float*)d_in[10];
    const float* c3w = (const float*)d_in[11];
    const float* c3b = (const float*)d_in[12];
    const float* c4w = (const float*)d_in[13];
    const float* c4b = (const float*)d_in[14];
    const float* f1w = (const float*)d_in[15];
    const float* f1b = (const float*)d_in[16];
    const float* hww = (const float*)d_in[17];
    const float* hbb = (const float*)d_in[18];
    float* out = (float*)d_out;

    char* ws = (char*)d_ws;
    short* locT   = (short*)(ws + 0);           // [512][512][112] bf16 (58.7 MB)
    short* embT   = (short*)(ws + 58720256);    // [100000][112] bf16 (22.4 MB)
    short* A1     = (short*)(ws + 81120256);    // 7*64*10*16 B each
    short* A2     = (short*)(ws + 81191936);
    short* A3     = (short*)(ws + 81263616);
    short* A4     = (short*)(ws + 81335296);    // 7*64*4*16 B
    float* zg     = (float*)(ws + 81363968);    // [512][112]
    float* logits = (float*)(ws + 81593344);    // [512][512]
    float* hpart  = (float*)(ws + 82641920);    // [512][8][2][112]

    emb_cvt_kernel<<<12500, 256, 0, stream>>>(emb, embT);
    pack_all_kernel<<<238, 64, 0, stream>>>(c1w, c2w, liw, c3w, A1, A2, A3, A4);

    size_t smemA = (size_t)2 * 72 * RS * 2;            // 36864 B -> 4 blocks/CU
    fused_conv_kernel<<<dim3(8, 512), 256, smemA, stream>>>(
        x, embT, A1, A2, A3, c1b, c2b, lib, locT, hpart);
    pool_gate_kernel<<<512, 128, 0, stream>>>(hpart, giw, gib, c3w, c3b, zg);
    size_t smemB = (size_t)128 * RS * 2 + 2 * 128 * 4; // 66560 B -> 2 blocks/CU
    conv3_logits_kernel<<<dim3(4, 512), 256, smemB, stream>>>(
        locT, A4, zg, c4w, c4b, logits);
    samp_head_kernel<<<512, 256, 0, stream>>>(
        u, logits, x, embT, f1w, f1b, hww, hbb, out + 512, out);
}

// Round 3
// 366.550 us; speedup vs baseline: 2.7760x; 1.5314x over previous
//
#include <hip/hip_runtime.h>
#include <math.h>

#define DEV __device__ __forceinline__

typedef __attribute__((ext_vector_type(8))) short short8;
typedef __attribute__((ext_vector_type(4))) short short4v;
typedef __attribute__((ext_vector_type(4))) float f32x4;
typedef __attribute__((ext_vector_type(2))) unsigned uint2v;

// LDS row stride in shorts (272 B = 68 words; 68 mod 32 = 4 -> b128 reads
// land 2-way on banks = free per m136). r0-proven layout.
#define SSTR 136
#define ROWB (16 * SSTR * 2)   // 4352 B per 16-row tile

DEV short f2bf(float f) {
    unsigned u = __builtin_bit_cast(unsigned, f);
    unsigned r = (u + 0x7fffu + ((u >> 16) & 1u)) >> 16;
    return (short)r;
}

#if __has_builtin(__builtin_amdgcn_cvt_pk_bf16_f32)
DEV unsigned pk2bf(float a, float b) {
    auto v = __builtin_amdgcn_cvt_pk_bf16_f32(a, b);
    return __builtin_bit_cast(unsigned, v);
}
#else
DEV unsigned pk2bf(float a, float b) {
    return ((unsigned)(unsigned short)f2bf(a)) |
           (((unsigned)(unsigned short)f2bf(b)) << 16);
}
#endif

DEV float bfu(short s) {
    unsigned u = ((unsigned)(unsigned short)s) << 16;
    return __builtin_bit_cast(float, u);
}

// ---------------------------------------------------------------------------
// emb f32 [V][100] -> bf16 [V][112], cols 100..111 zeroed. 8 rows/block.
// ---------------------------------------------------------------------------
__global__ __launch_bounds__(256) void emb_cvt_kernel(
    const float* __restrict__ emb, short* __restrict__ embT) {
    int t = threadIdx.x;
    int row = blockIdx.x * 8 + (t >> 5);
    int c4 = t & 31;
    if (c4 >= 28) return;
    short4v v = {0, 0, 0, 0};
    if (c4 < 25) {
        f32x4 e = *(const f32x4*)&emb[row * 100 + c4 * 4];
#pragma unroll
        for (int r = 0; r < 4; ++r) v[r] = f2bf(e[r]);
    }
    *(short4v*)&embT[row * 112 + c4 * 4] = v;
}

// ---------------------------------------------------------------------------
// Pack conv weights into MFMA A-fragment order.
// Layout: [fblk*64 + lane][ks] contiguous in ks -> K-loop A-loads are ONE
// base address per mt + imm offsets ks*16B (0..144).
// mode 0 (3-tap): 13 octets per tap; K = 320 (10 ks).
// mode 1 (conv3 loc half): kappa = c (cols 100..199 of w[100][200]), K 128.
// ---------------------------------------------------------------------------
__global__ __launch_bounds__(64) void pack_all_kernel(
    const float* __restrict__ c1w, const float* __restrict__ c2w,
    const float* __restrict__ liw, const float* __restrict__ c3w,
    short* __restrict__ A1, short* __restrict__ A2,
    short* __restrict__ A3, short* __restrict__ A4) {
    int bx = blockIdx.x;
    const float* w; short* dst; int mode, lbx;
    if (bx < 70)       { w = c1w; dst = A1; mode = 0; lbx = bx; }
    else if (bx < 140) { w = c2w; dst = A2; mode = 0; lbx = bx - 70; }
    else if (bx < 210) { w = liw; dst = A3; mode = 0; lbx = bx - 140; }
    else               { w = c3w; dst = A4; mode = 1; lbx = bx - 210; }
    int lane = threadIdx.x;
    int fblk = lbx % 7, ksb = lbx / 7;
    int f = fblk * 16 + (lane & 15);
    int kb = ksb * 32 + (lane >> 4) * 8;
    int nks = (mode == 0) ? 10 : 4;
    short8 v;
#pragma unroll
    for (int j = 0; j < 8; ++j) {
        int kk = kb + j;
        float val = 0.f;
        if (f < 100) {
            if (mode == 0) {
                int oct = kk >> 3, dk = oct / 13;
                int c = (oct - 13 * dk) * 8 + (kk & 7);
                if (dk < 3 && c < 100) val = w[(f * 100 + c) * 3 + dk];
            } else {
                if (kk < 100) val = w[f * 200 + 100 + kk];
            }
        }
        v[j] = f2bf(val);
    }
    *(short8*)&dst[((fblk * 64 + lane) * nks + ksb) * 8] = v;
}

// ---------------------------------------------------------------------------
// One 3-tap conv pass. ROW-BAND tiling: wave owns mt [MTB,MTB+MT) x
// nt [NTB,NTB+NT). With MT in {2,2,2,1} x NT=5 the per-pass critical path is
// 10 MFMA-tiles/ks (was 12 with the old 12/8/9/6 split) -> barriers wait 17%
// less. Accumulator init = bias. CLAMPL: the nt==4 tile reads clamped rows
// (feeds only discarded outputs; halo chain loc<=63 -> c2<=65 -> h<=67 ->
// e<=69 all real). EDGE: l-range zeroing only in bx 0/7. POOL: relu partial
// sums for l in [l0,l0+64) -> hpart_slot[112] (waves own disjoint f-ranges).
// ---------------------------------------------------------------------------
template<int MT, int NT, int MTB, int NTB, bool CLAMPL, bool POOL,
         bool TO_GLOBAL, bool EDGE>
DEV void ctap(const short* __restrict__ Ap, const short* s_src, short* s_dst,
              short* __restrict__ gout, const int* bofs, const int* bofs4,
              const float* __restrict__ bias, int row0l, int l0,
              float* __restrict__ hpart_slot, int lane) {
    const int q = lane >> 4, n = lane & 15;
    const f32x4 z4 = {0.f, 0.f, 0.f, 0.f};
    f32x4 acc[MT][NT];
#pragma unroll
    for (int mt = 0; mt < MT; ++mt) {
        int fb = (MTB + mt) * 16 + q * 4;
        f32x4 bs = (fb < 100) ? *(const f32x4*)&bias[fb] : z4;
#pragma unroll
        for (int nt = 0; nt < NT; ++nt) acc[mt][nt] = bs;
    }
#pragma unroll
    for (int ks = 0; ks < 10; ++ks) {
        short8 a[MT];
#pragma unroll
        for (int mt = 0; mt < MT; ++mt)
            a[mt] = *(const short8*)&Ap[(((MTB + mt) * 64 + lane) * 10 + ks) * 8];
        const char* bp = (const char*)s_src + bofs[ks];
        short8 bf[NT];
#pragma unroll
        for (int nt = 0; nt < NT; ++nt) {
            if (CLAMPL && (NTB + nt) == 4)
                bf[nt] = *(const short8*)((const char*)s_src + bofs4[ks]);
            else
                bf[nt] = *(const short8*)(bp + (NTB + nt) * ROWB);
        }
#pragma unroll
        for (int mt = 0; mt < MT; ++mt)
#pragma unroll
            for (int nt = 0; nt < NT; ++nt)
                acc[mt][nt] = __builtin_amdgcn_mfma_f32_16x16x32_bf16(
                    a[mt], bf[nt], acc[mt][nt], 0, 0, 0);
    }
    f32x4 ps[MT];
    if constexpr (POOL) {
#pragma unroll
        for (int mt = 0; mt < MT; ++mt) ps[mt] = z4;
    }
#pragma unroll
    for (int nt = 0; nt < NT; ++nt) {
        const int j = (NTB + nt) * 16 + n;
        const int l = row0l + j;
        bool lok = true;
        if constexpr (EDGE) lok = ((unsigned)l < 512u);
        const bool pok = POOL && (l >= l0) && (l < l0 + 64);
#pragma unroll
        for (int mt = 0; mt < MT; ++mt) {
            const int fb = (MTB + mt) * 16 + q * 4;
            f32x4 v;
#pragma unroll
            for (int r = 0; r < 4; ++r) {
                v[r] = fmaxf(acc[mt][nt][r], 0.f);
                if constexpr (EDGE) v[r] = lok ? v[r] : 0.f;
            }
            if constexpr (POOL) {
                if (pok) {
#pragma unroll
                    for (int r = 0; r < 4; ++r) ps[mt][r] += v[r];
                }
            }
            uint2v pk;
            pk[0] = pk2bf(v[0], v[1]); pk[1] = pk2bf(v[2], v[3]);
            if constexpr (TO_GLOBAL) {
                *(uint2v*)&gout[j * 112 + fb] = pk;
            } else {
                if ((NTB + nt) < 4 || n < 6)      // store rows j < 70 only
                    *(uint2v*)&s_dst[j * SSTR + fb] = pk;
            }
        }
    }
    if constexpr (POOL) {
#pragma unroll
        for (int mt = 0; mt < MT; ++mt)
#pragma unroll
            for (int off = 1; off <= 8; off <<= 1)
#pragma unroll
                for (int r = 0; r < 4; ++r)
                    ps[mt][r] += __shfl_xor(ps[mt][r], off, 64);
        if (n == 0) {
#pragma unroll
            for (int mt = 0; mt < MT; ++mt)
                *(f32x4*)&hpart_slot[(MTB + mt) * 16 + q * 4] = ps[mt];
        }
    }
}

// ---------------------------------------------------------------------------
// Fused conv1 -> conv2 -> li, 64-wide l-tile, 256 threads (4 waves), grid
// (8,512). Staging = VGPR gather + ds_write (global_load_lds is NOT usable
// here: scattered per-lane sources serialize the LDS-DMA -- measured 3.6x
// regression in r2). Row-band wave tiles: wv0/1/2 = 2 f-rows x 5 nt,
// wv3 = 1 f-row x 5 nt; li: 2/2/2/1 f-rows x 4 nt.
// LDS 2*72*SSTR*2 = 39168 B -> 4 blocks/CU.
// ---------------------------------------------------------------------------
__global__ __launch_bounds__(256, 4) void fused_conv_kernel(
    const int* __restrict__ xidx, const short* __restrict__ embT,
    const short* __restrict__ A1, const short* __restrict__ A2,
    const short* __restrict__ A3,
    const float* __restrict__ b1, const float* __restrict__ b2,
    const float* __restrict__ b3,
    short* __restrict__ locT, float* __restrict__ hpart) {
    extern __shared__ char smem[];
    short* s_e = (short*)smem;                    // [72][SSTR], later c2
    short* s_h = (short*)(smem + 72 * SSTR * 2);  // [72][SSTR]
    const int tid = threadIdx.x;
    const int b = blockIdx.y, bx = blockIdx.x, l0 = bx * 64;
    const int lane = tid & 63, wv = tid >> 6;
    const int q = lane >> 4, n = lane & 15;

    // stage e: 70 rows x 14 b128 chunks (virtual 16-grid; c8>=14 skipped)
#pragma unroll
    for (int p = 0; p < 5; ++p) {
        int idx = tid + p * 256;           // 0..1279, need j<70
        int j = idx >> 4, c8 = idx & 15;
        if (j < 70 && c8 < 14) {
            int lg = l0 - 3 + j;
            short8 v = {0, 0, 0, 0, 0, 0, 0, 0};
            if (lg >= 0 && lg < 512) {
                int row = xidx[b * 512 + lg];
                v = *(const short8*)&embT[row * 112 + c8 * 8];
            }
            *(short8*)&s_e[j * SSTR + c8 * 8] = v;
        }
    }

    // per-lane B byte offsets for all 10 k-steps (row n+dk, col c0)
    int bofs[10], bofs4[10];
#pragma unroll
    for (int ks = 0; ks < 10; ++ks) {
        int oct = ks * 4 + q;
        int dk = (oct >= 39) ? 3 : (oct >= 26) ? 2 : (oct >= 13) ? 1 : 0;
        int c0 = (oct - 13 * dk) * 8;
        bofs[ks] = ((n + dk) * SSTR + c0) * 2;
        int r4 = 64 + n + dk; if (r4 > 69) r4 = 69;  // discarded rows only
        bofs4[ks] = (r4 * SSTR + c0) * 2;
    }
    float* hps = hpart + (b * 8 + bx) * 112;      // waves write disjoint f
    short* gouts = locT + ((size_t)b * 512 + l0) * 112;

    __syncthreads();
    const bool edge = (bx == 0) || (bx == 7);

#define PASS3T(Ap, SRC, DST, BIAS, R0L, PL, E)                                   \
    if (wv == 0)      ctap<2,5,0,0,true,PL,false,E>(Ap,SRC,DST,nullptr,bofs,bofs4,BIAS,R0L,l0,hps,lane); \
    else if (wv == 1) ctap<2,5,2,0,true,PL,false,E>(Ap,SRC,DST,nullptr,bofs,bofs4,BIAS,R0L,l0,hps,lane); \
    else if (wv == 2) ctap<2,5,4,0,true,PL,false,E>(Ap,SRC,DST,nullptr,bofs,bofs4,BIAS,R0L,l0,hps,lane); \
    else              ctap<1,5,6,0,true,PL,false,E>(Ap,SRC,DST,nullptr,bofs,bofs4,BIAS,R0L,l0,hps,lane);

    if (edge) {
        PASS3T(A1, s_e, s_h, b1, l0 - 2, true, true)
        __syncthreads();
        PASS3T(A2, s_h, s_e, b2, l0 - 1, false, true)
    } else {
        PASS3T(A1, s_e, s_h, b1, l0 - 2, true, false)
        __syncthreads();
        PASS3T(A2, s_h, s_e, b2, l0 - 1, false, false)
    }
    __syncthreads();
    // li: outputs l in [l0, l0+63] always valid
    if (wv == 0)      ctap<2,4,0,0,false,false,true,false>(A3,s_e,nullptr,gouts,bofs,bofs4,b3,l0,l0,hps,lane);
    else if (wv == 1) ctap<2,4,2,0,false,false,true,false>(A3,s_e,nullptr,gouts,bofs,bofs4,b3,l0,l0,hps,lane);
    else if (wv == 2) ctap<2,4,4,0,false,false,true,false>(A3,s_e,nullptr,gouts,bofs,bofs4,b3,l0,l0,hps,lane);
    else              ctap<1,4,6,0,false,false,true,false>(A3,s_e,nullptr,gouts,bofs,bofs4,b3,l0,l0,hps,lane);
#undef PASS3T
}

// ---------------------------------------------------------------------------
// conv3 (1x1, loc half) + conv4 fused -> logits. 128-l tile; COLUMN-BAND
// tiling: each wave owns ALL 7 f-rows x 2 nt cols (max 14 MFMA-tiles/ks,
// was 16) -> each wave produces COMPLETE logits for its 32 columns, no
// cross-wave partial sum. LDS 128*SSTR*2 + 512 = 35328 B -> 4 blocks/CU.
// ---------------------------------------------------------------------------
template<int NTB>
DEV void c3tile(const short* s_in, float* s_part, const short* __restrict__ A4,
                const float* __restrict__ zg, const float* __restrict__ w4,
                int bb, int lane) {
    const int q = lane >> 4, n = lane & 15;
    const f32x4 z4 = {0.f, 0.f, 0.f, 0.f};
    f32x4 acc[7][2];
#pragma unroll
    for (int mt = 0; mt < 7; ++mt) {
        int fb = mt * 16 + q * 4;
        f32x4 zgv = *(const f32x4*)&zg[bb * 112 + fb];  // pad entries are 0
#pragma unroll
        for (int nt = 0; nt < 2; ++nt) acc[mt][nt] = zgv;
    }
#pragma unroll
    for (int ks = 0; ks < 4; ++ks) {
        short8 a[7];
#pragma unroll
        for (int mt = 0; mt < 7; ++mt)
            a[mt] = *(const short8*)&A4[((mt * 64 + lane) * 4 + ks) * 8];
        int c0 = (ks * 4 + q) * 8;
        if (c0 > 104) c0 = 104;   // A zero for kappa>=100
        const char* bp = (const char*)(s_in + n * SSTR + c0);
        short8 bf[2];
#pragma unroll
        for (int nt = 0; nt < 2; ++nt)
            bf[nt] = *(const short8*)(bp + (NTB + nt) * ROWB);
#pragma unroll
        for (int mt = 0; mt < 7; ++mt)
#pragma unroll
            for (int nt = 0; nt < 2; ++nt)
                acc[mt][nt] = __builtin_amdgcn_mfma_f32_16x16x32_bf16(
                    a[mt], bf[nt], acc[mt][nt], 0, 0, 0);
    }
#pragma unroll
    for (int nt = 0; nt < 2; ++nt) {
        float part = 0.f;
#pragma unroll
        for (int mt = 0; mt < 7; ++mt) {
            const int fb = mt * 16 + q * 4;
            f32x4 w4v = (fb < 100) ? *(const f32x4*)&w4[fb] : z4;
#pragma unroll
            for (int r = 0; r < 4; ++r)
                part += fmaxf(acc[mt][nt][r], 0.f) * w4v[r];
        }
        part += __shfl_xor(part, 16, 64);
        part += __shfl_xor(part, 32, 64);
        if (q == 0) s_part[(NTB + nt) * 16 + n] = part;   // full logit
    }
}

__global__ __launch_bounds__(256, 4) void conv3_logits_kernel(
    const short* __restrict__ locT, const short* __restrict__ A4,
    const float* __restrict__ zg, const float* __restrict__ w4,
    const float* __restrict__ b4, float* __restrict__ logits) {
    extern __shared__ char smem[];
    short* s_in = (short*)smem;                     // [128][SSTR]
    float* s_part = (float*)(smem + 128 * SSTR * 2);  // [128]
    const int tid = threadIdx.x;
    const int b = blockIdx.y, l0r = blockIdx.x * 128;
    const int lane = tid & 63, wv = tid >> 6;

    {
        short8 tmp[8];
#pragma unroll
        for (int p = 0; p < 8; ++p) {
            int idx = tid + p * 256;
            int j = idx >> 4, c8 = idx & 15;
            if (c8 < 14)
                tmp[p] = *(const short8*)&locT[((size_t)b * 512 + l0r + j) * 112 + c8 * 8];
        }
#pragma unroll
        for (int p = 0; p < 8; ++p) {
            int idx = tid + p * 256;
            int j = idx >> 4, c8 = idx & 15;
            if (c8 < 14)
                *(short8*)&s_in[j * SSTR + c8 * 8] = tmp[p];
        }
    }
    __syncthreads();
    if (wv == 0)      c3tile<0>(s_in, s_part, A4, zg, w4, b, lane);
    else if (wv == 1) c3tile<2>(s_in, s_part, A4, zg, w4, b, lane);
    else if (wv == 2) c3tile<4>(s_in, s_part, A4, zg, w4, b, lane);
    else              c3tile<6>(s_in, s_part, A4, zg, w4, b, lane);
    __syncthreads();
    if (tid < 128)
        logits[b * 512 + l0r + tid] = s_part[tid] + b4[0];
}

// ---------------------------------------------------------------------------
// Finish pool: hm = sum over 8 block-slot partials / 512, gate MLP, fold g:
// zg[b,f] = conv3_b[f] + sum_h g[b,h] * w3[f][h]   (f>=100 -> 0)
// ---------------------------------------------------------------------------
__global__ __launch_bounds__(128) void pool_gate_kernel(
    const float* __restrict__ hpart, const float* __restrict__ gi_w,
    const float* __restrict__ gi_b, const float* __restrict__ w3,
    const float* __restrict__ b3, float* __restrict__ zg) {
    int b = blockIdx.x, tid = threadIdx.x;
    __shared__ float s_hm[112];
    __shared__ float s_g[100];
    if (tid < 112) {
        float a = 0.f;
#pragma unroll
        for (int s = 0; s < 8; ++s) a += hpart[(b * 8 + s) * 112 + tid];
        s_hm[tid] = a * (1.f / 512.f);
    }
    __syncthreads();
    if (tid < 100) {
        float a = gi_b[tid];
        for (int f = 0; f < 100; ++f) a += s_hm[f] * gi_w[tid * 100 + f];
        s_g[tid] = fmaxf(a, 0.f);
    }
    __syncthreads();
    if (tid < 112) {
        float a = 0.f;
        if (tid < 100) {
            a = b3[tid];
            for (int h = 0; h < 100; ++h) a += s_g[h] * w3[tid * 200 + h];
        }
        zg[b * 112 + tid] = a;
    }
}

// ---------------------------------------------------------------------------
// Fused sampler + distil head, one block per b. Wave-parallel over k:
// wave wv handles k = wv, wv+4, wv+8 (<10) with wave-local shuffle softmax
// (no barriers inside the k loop). Merge via LDS max, then pooled gather
// (bf16 embT), fc1 relu, sigmoid head.
// ---------------------------------------------------------------------------
__global__ __launch_bounds__(256) void samp_head_kernel(
    const float* __restrict__ u, const float* __restrict__ logits,
    const int* __restrict__ xidx, const short* __restrict__ embT,
    const float* __restrict__ f1w, const float* __restrict__ f1b,
    const float* __restrict__ hw, const float* __restrict__ hb,
    float* __restrict__ cs_out, float* __restrict__ out) {
    const float EPSV = 1.1920929e-07f;
    const float INVT = 1.f / 0.3f;
    int b = blockIdx.x, tid = threadIdx.x;
    int lane = tid & 63, wv = tid >> 6;
    __shared__ float s_logT[512], s_cs[512];
    __shared__ int s_x[512];
    __shared__ float s_csw[4][512];
    __shared__ float s_acc[16][112];
    __shared__ float s_pool[112], s_h2[100], s_fin[4];
    for (int l = tid; l < 512; l += 256) {
        s_logT[l] = logits[b * 512 + l] * INVT;
        s_x[l] = xidx[b * 512 + l];
    }
    __syncthreads();
    // wave-local softmax per k
    const int nk = (wv < 2) ? 3 : 2;
    float csl[8];
#pragma unroll
    for (int i = 0; i < 8; ++i) csl[i] = 0.f;
    float lt[8];
#pragma unroll
    for (int i = 0; i < 8; ++i) lt[i] = s_logT[lane * 8 + i];
    for (int j = 0; j < nk; ++j) {
        int k = wv + 4 * j;
        f32x4 u0 = *(const f32x4*)&u[(b * 10 + k) * 512 + lane * 8];
        f32x4 u1 = *(const f32x4*)&u[(b * 10 + k) * 512 + lane * 8 + 4];
        float nz[8];
#pragma unroll
        for (int i = 0; i < 8; ++i) {
            float vv = (i < 4) ? u0[i] : u1[i - 4];
            vv = fminf(fmaxf(vv, EPSV), 1.f - EPSV);
            nz[i] = -__logf(-__logf(vv)) * INVT + lt[i];
        }
        float m = nz[0];
#pragma unroll
        for (int i = 1; i < 8; ++i) m = fmaxf(m, nz[i]);
#pragma unroll
        for (int off = 1; off <= 32; off <<= 1) m = fmaxf(m, __shfl_xor(m, off, 64));
        float e[8], s = 0.f;
#pragma unroll
        for (int i = 0; i < 8; ++i) { e[i] = __expf(nz[i] - m); s += e[i]; }
#pragma unroll
        for (int off = 1; off <= 32; off <<= 1) s += __shfl_xor(s, off, 64);
        float inv = 1.f / s;
#pragma unroll
        for (int i = 0; i < 8; ++i) csl[i] = fmaxf(csl[i], e[i] * inv);
    }
#pragma unroll
    for (int i = 0; i < 8; ++i) s_csw[wv][lane * 8 + i] = csl[i];
    __syncthreads();
    for (int l = tid; l < 512; l += 256) {
        float c = fmaxf(fmaxf(s_csw[0][l], s_csw[1][l]),
                        fmaxf(s_csw[2][l], s_csw[3][l]));
        s_cs[l] = c;
        cs_out[b * 512 + l] = c;
    }
    __syncthreads();
    // pooled partial sums: thread (jg, c8) covers l = jg+16t, channels c8*8..+7
    int jg = tid >> 4, c8 = tid & 15;
    if (c8 < 14) {
        f32x4 pa = {0.f, 0.f, 0.f, 0.f}, pb = {0.f, 0.f, 0.f, 0.f};
#pragma unroll 4
        for (int l = jg; l < 512; l += 16) {
            int row = s_x[l];
            float cv = s_cs[l];
            short8 e8 = *(const short8*)&embT[(size_t)row * 112 + c8 * 8];
#pragma unroll
            for (int r = 0; r < 4; ++r) {
                pa[r] += cv * bfu(e8[r]);
                pb[r] += cv * bfu(e8[4 + r]);
            }
        }
        *(f32x4*)&s_acc[jg][c8 * 8] = pa;
        *(f32x4*)&s_acc[jg][c8 * 8 + 4] = pb;
    }
    __syncthreads();
    if (tid < 112) {
        float p = 0.f;
#pragma unroll
        for (int g = 0; g < 16; ++g) p += s_acc[g][tid];
        s_pool[tid] = p * (1.f / 512.f);
    }
    __syncthreads();
    if (tid < 100) {
        float a = f1b[tid];
        for (int i = 0; i < 100; ++i) a += s_pool[i] * f1w[tid * 100 + i];
        s_h2[tid] = fmaxf(a, 0.f);
    }
    __syncthreads();
    float v = (tid < 100) ? s_h2[tid] * hw[tid] : 0.f;
#pragma unroll
    for (int off = 32; off >= 1; off >>= 1) v += __shfl_xor(v, off, 64);
    if (lane == 0) s_fin[wv] = v;
    __syncthreads();
    if (tid == 0) {
        float z = s_fin[0] + s_fin[1] + s_fin[2] + s_fin[3] + hb[0];
        out[b] = 1.f / (1.f + __expf(-z));
    }
}

// ---------------------------------------------------------------------------
extern "C" void kernel_launch(void* const* d_in, const int* in_sizes, int n_in,
                              void* d_out, int out_size, void* d_ws, size_t ws_size,
                              hipStream_t stream) {
    const int*   x   = (const int*)d_in[0];
    const float* u   = (const float*)d_in[1];
    const float* emb = (const float*)d_in[2];
    const float* c1w = (const float*)d_in[3];
    const float* c1b = (const float*)d_in[4];
    const float* giw = (const float*)d_in[5];
    const float* gib = (const float*)d_in[6];
    const float* c2w = (const float*)d_in[7];
    const float* c2b = (const float*)d_in[8];
    const float* liw = (const float*)d_in[9];
    const float* lib = (const float*)d_in[10];
    const float* c3w = (const float*)d_in[11];
    const float* c3b = (const float*)d_in[12];
    const float* c4w = (const float*)d_in[13];
    const float* c4b = (const float*)d_in[14];
    const float* f1w = (const float*)d_in[15];
    const float* f1b = (const float*)d_in[16];
    const float* hww = (const float*)d_in[17];
    const float* hbb = (const float*)d_in[18];
    float* out = (float*)d_out;

    char* ws = (char*)d_ws;
    short* locT   = (short*)(ws + 0);           // [512][512][112] bf16 (58.7 MB)
    short* embT   = (short*)(ws + 58720256);    // [100000][112] bf16 (22.4 MB)
    short* A1     = (short*)(ws + 81120256);    // 7*64*10*16 B each
    short* A2     = (short*)(ws + 81191936);
    short* A3     = (short*)(ws + 81263616);
    short* A4     = (short*)(ws + 81335296);    // 7*64*4*16 B
    float* zg     = (float*)(ws + 81363968);    // [512][112]
    float* logits = (float*)(ws + 81593344);    // [512][512]
    float* hpart  = (float*)(ws + 82641920);    // [512][8][112]

    emb_cvt_kernel<<<12500, 256, 0, stream>>>(emb, embT);
    pack_all_kernel<<<238, 64, 0, stream>>>(c1w, c2w, liw, c3w, A1, A2, A3, A4);

    size_t smemA = 2 * 72 * SSTR * 2;             // 39168 B -> 4 blocks/CU
    fused_conv_kernel<<<dim3(8, 512), 256, smemA, stream>>>(
        x, embT, A1, A2, A3, c1b, c2b, lib, locT, hpart);
    pool_gate_kernel<<<512, 128, 0, stream>>>(hpart, giw, gib, c3w, c3b, zg);
    size_t smemB = 128 * SSTR * 2 + 128 * 4;      // 35328 B -> 4 blocks/CU
    conv3_logits_kernel<<<dim3(4, 512), 256, smemB, stream>>>(
        locT, A4, zg, c4w, c4b, logits);
    samp_head_kernel<<<512, 256, 0, stream>>>(
        u, logits, x, embT, f1w, f1b, hww, hbb, out + 512, out);
}

// Round 4
// 358.089 us; speedup vs baseline: 2.8416x; 1.0236x over previous
//
#include <hip/hip_runtime.h>
#include <math.h>

#define DEV __device__ __forceinline__

typedef __attribute__((ext_vector_type(8))) short short8;
typedef __attribute__((ext_vector_type(4))) short short4v;
typedef __attribute__((ext_vector_type(4))) float f32x4;
typedef __attribute__((ext_vector_type(2))) unsigned uint2v;

// LDS row stride in shorts. 114 shorts = 228 B = 57 words; 57 is odd ->
// gcd(57,32)=1 -> consecutive rows start at all-distinct banks (uniform
// spread for the 16-row B-read pattern, same quality as the old 136).
// 114 (vs 136) shrinks the double buffer to 2*70*114*2 = 31920 B -> 5
// blocks/CU (was 4): occupancy ceiling 50% -> 62.5%.
#define SSTR 114
#define ROWB (16 * SSTR * 2)   // bytes per 16-row tile

DEV short f2bf(float f) {
    unsigned u = __builtin_bit_cast(unsigned, f);
    unsigned r = (u + 0x7fffu + ((u >> 16) & 1u)) >> 16;
    return (short)r;
}

#if __has_builtin(__builtin_amdgcn_cvt_pk_bf16_f32)
DEV unsigned pk2bf(float a, float b) {
    auto v = __builtin_amdgcn_cvt_pk_bf16_f32(a, b);
    return __builtin_bit_cast(unsigned, v);
}
#else
DEV unsigned pk2bf(float a, float b) {
    return ((unsigned)(unsigned short)f2bf(a)) |
           (((unsigned)(unsigned short)f2bf(b)) << 16);
}
#endif

DEV float bfu(short s) {
    unsigned u = ((unsigned)(unsigned short)s) << 16;
    return __builtin_bit_cast(float, u);
}

// ---------------------------------------------------------------------------
// emb f32 [V][100] -> bf16 [V][112], cols 100..111 zeroed. 8 rows/block.
// ---------------------------------------------------------------------------
__global__ __launch_bounds__(256) void emb_cvt_kernel(
    const float* __restrict__ emb, short* __restrict__ embT) {
    int t = threadIdx.x;
    int row = blockIdx.x * 8 + (t >> 5);
    int c4 = t & 31;
    if (c4 >= 28) return;
    short4v v = {0, 0, 0, 0};
    if (c4 < 25) {
        f32x4 e = *(const f32x4*)&emb[row * 100 + c4 * 4];
#pragma unroll
        for (int r = 0; r < 4; ++r) v[r] = f2bf(e[r]);
    }
    *(short4v*)&embT[row * 112 + c4 * 4] = v;
}

// ---------------------------------------------------------------------------
// Pack conv weights into MFMA A-fragment order (r0-proven [ks][fblk][lane]
// layout: per (ks,mt) a wave's 64 lanes read one contiguous 1 KB line).
// mode 0 (3-tap): 13 octets per tap -> oct=kk>>3, dk=oct/13,
//   c=(oct-13*dk)*8+(kk&7); K = 320 (10 ks).
// mode 1 (conv3 loc half): kappa = c (cols 100..199 of w[100][200]), K 128.
// ---------------------------------------------------------------------------
__global__ __launch_bounds__(64) void pack_all_kernel(
    const float* __restrict__ c1w, const float* __restrict__ c2w,
    const float* __restrict__ liw, const float* __restrict__ c3w,
    short* __restrict__ A1, short* __restrict__ A2,
    short* __restrict__ A3, short* __restrict__ A4) {
    int bx = blockIdx.x;
    const float* w; short* dst; int mode, lbx;
    if (bx < 70)       { w = c1w; dst = A1; mode = 0; lbx = bx; }
    else if (bx < 140) { w = c2w; dst = A2; mode = 0; lbx = bx - 70; }
    else if (bx < 210) { w = liw; dst = A3; mode = 0; lbx = bx - 140; }
    else               { w = c3w; dst = A4; mode = 1; lbx = bx - 210; }
    int lane = threadIdx.x;
    int f = lbx % 7 * 16 + (lane & 15);
    int kb = (lbx / 7) * 32 + (lane >> 4) * 8;
    short8 v;
#pragma unroll
    for (int j = 0; j < 8; ++j) {
        int kk = kb + j;
        float val = 0.f;
        if (f < 100) {
            if (mode == 0) {
                int oct = kk >> 3, dk = oct / 13;
                int c = (oct - 13 * dk) * 8 + (kk & 7);
                if (dk < 3 && c < 100) val = w[(f * 100 + c) * 3 + dk];
            } else {
                if (kk < 100) val = w[f * 200 + 100 + kk];
            }
        }
        v[j] = f2bf(val);
    }
    *(short8*)&dst[(lbx * 64 + lane) * 8] = v;
}

// ---------------------------------------------------------------------------
// One 3-tap conv pass, BALANCED tile (r0-proven): this wave owns
// mt [MTB,MTB+MT) x nt [NTB,NTB+NT). B-reads amortize over MT MFMAs,
// A-rows over NT. Accumulator init = bias. CLAMPL: the nt==4 tile reads
// clamped rows (feeds only discarded outputs; halo chain loc<=63 -> c2<=65
// -> h<=67 -> e<=69 all real). EDGE: l-range zeroing only in bx 0/7.
// POOL: relu partial sums for l in [l0,l0+64) -> hpart_slot[112].
// ---------------------------------------------------------------------------
template<int MT, int NT, int MTB, int NTB, bool CLAMPL, bool POOL,
         bool TO_GLOBAL, bool EDGE>
DEV void ctap(const short* __restrict__ Ap, const short* s_src, short* s_dst,
              short* __restrict__ gout, const int* bofs, const int* bofs4,
              const float* __restrict__ bias, int row0l, int l0,
              float* __restrict__ hpart_slot, int lane) {
    const int q = lane >> 4, n = lane & 15;
    const f32x4 z4 = {0.f, 0.f, 0.f, 0.f};
    f32x4 acc[MT][NT];
#pragma unroll
    for (int mt = 0; mt < MT; ++mt) {
        int fb = (MTB + mt) * 16 + q * 4;
        f32x4 bs = (fb < 100) ? *(const f32x4*)&bias[fb] : z4;
#pragma unroll
        for (int nt = 0; nt < NT; ++nt) acc[mt][nt] = bs;
    }
#pragma unroll
    for (int ks = 0; ks < 10; ++ks) {
        short8 a[MT];
#pragma unroll
        for (int mt = 0; mt < MT; ++mt)
            a[mt] = *(const short8*)&Ap[(ks * 448 + (MTB + mt) * 64 + lane) * 8];
        const char* bp = (const char*)s_src + bofs[ks];
        short8 bf[NT];
#pragma unroll
        for (int nt = 0; nt < NT; ++nt) {
            if (CLAMPL && (NTB + nt) == 4)
                bf[nt] = *(const short8*)((const char*)s_src + bofs4[ks]);
            else
                bf[nt] = *(const short8*)(bp + (NTB + nt) * ROWB);
        }
#pragma unroll
        for (int mt = 0; mt < MT; ++mt)
#pragma unroll
            for (int nt = 0; nt < NT; ++nt)
                acc[mt][nt] = __builtin_amdgcn_mfma_f32_16x16x32_bf16(
                    a[mt], bf[nt], acc[mt][nt], 0, 0, 0);
    }
    f32x4 ps[MT];
    if constexpr (POOL) {
#pragma unroll
        for (int mt = 0; mt < MT; ++mt) ps[mt] = z4;
    }
#pragma unroll
    for (int nt = 0; nt < NT; ++nt) {
        const int j = (NTB + nt) * 16 + n;
        const int l = row0l + j;
        bool lok = true;
        if constexpr (EDGE) lok = ((unsigned)l < 512u);
        const bool pok = POOL && (l >= l0) && (l < l0 + 64);
#pragma unroll
        for (int mt = 0; mt < MT; ++mt) {
            const int fb = (MTB + mt) * 16 + q * 4;
            f32x4 v;
#pragma unroll
            for (int r = 0; r < 4; ++r) {
                v[r] = fmaxf(acc[mt][nt][r], 0.f);
                if constexpr (EDGE) v[r] = lok ? v[r] : 0.f;
            }
            if constexpr (POOL) {
                if (pok) {
#pragma unroll
                    for (int r = 0; r < 4; ++r) ps[mt][r] += v[r];
                }
            }
            uint2v pk;
            pk[0] = pk2bf(v[0], v[1]); pk[1] = pk2bf(v[2], v[3]);
            if constexpr (TO_GLOBAL) {
                *(uint2v*)&gout[j * 112 + fb] = pk;
            } else {
                if ((NTB + nt) < 4 || n < 6)      // store rows j < 70 only
                    *(uint2v*)&s_dst[j * SSTR + fb] = pk;
            }
        }
    }
    if constexpr (POOL) {
#pragma unroll
        for (int mt = 0; mt < MT; ++mt)
#pragma unroll
            for (int off = 1; off <= 8; off <<= 1)
#pragma unroll
                for (int r = 0; r < 4; ++r)
                    ps[mt][r] += __shfl_xor(ps[mt][r], off, 64);
        if (n == 0) {
#pragma unroll
            for (int mt = 0; mt < MT; ++mt)
                *(f32x4*)&hpart_slot[(MTB + mt) * 16 + q * 4] = ps[mt];
        }
    }
}

// ---------------------------------------------------------------------------
// Fused conv1 -> conv2 -> li, 64-wide l-tile, 256 threads (4 waves), grid
// (8,512) -- the r0-proven structure. Staging = VGPR gather + ds_write
// (global_load_lds with scattered sources serializes the LDS-DMA: measured
// 3.6x regression in r2). Balanced wave tiles: wv0=(4,3)@(0,0) wv1=(4,2)@(0,3)
// wv2=(3,3)@(4,0) wv3=(3,2)@(4,3); li: NT=2 each @(0/4, 0/2).
// LDS 2*70*SSTR*2 = 31920 B -> 5 blocks/CU (20 waves/CU).
// ---------------------------------------------------------------------------
__global__ __launch_bounds__(256, 5) void fused_conv_kernel(
    const int* __restrict__ xidx, const short* __restrict__ embT,
    const short* __restrict__ A1, const short* __restrict__ A2,
    const short* __restrict__ A3,
    const float* __restrict__ b1, const float* __restrict__ b2,
    const float* __restrict__ b3,
    short* __restrict__ locT, float* __restrict__ hpart) {
    extern __shared__ char smem[];
    short* s_e = (short*)smem;                    // [70][SSTR], later c2
    short* s_h = (short*)(smem + 70 * SSTR * 2);  // [70][SSTR]
    const int tid = threadIdx.x;
    const int b = blockIdx.y, bx = blockIdx.x, l0 = bx * 64;
    const int lane = tid & 63, wv = tid >> 6;
    const int q = lane >> 4, n = lane & 15;

    // stage e: 70 rows x 14 b128 chunks (virtual 16-grid; c8>=14 skipped)
#pragma unroll
    for (int p = 0; p < 5; ++p) {
        int idx = tid + p * 256;           // 0..1279, need j<70
        int j = idx >> 4, c8 = idx & 15;
        if (j < 70 && c8 < 14) {
            int lg = l0 - 3 + j;
            short8 v = {0, 0, 0, 0, 0, 0, 0, 0};
            if (lg >= 0 && lg < 512) {
                int row = xidx[b * 512 + lg];
                v = *(const short8*)&embT[row * 112 + c8 * 8];
            }
            *(short8*)&s_e[j * SSTR + c8 * 8] = v;
        }
    }

    // per-lane B byte offsets for all 10 k-steps (row n+dk, col c0)
    int bofs[10], bofs4[10];
#pragma unroll
    for (int ks = 0; ks < 10; ++ks) {
        int oct = ks * 4 + q;
        int dk = (oct >= 39) ? 3 : (oct >= 26) ? 2 : (oct >= 13) ? 1 : 0;
        int c0 = (oct - 13 * dk) * 8;
        bofs[ks] = ((n + dk) * SSTR + c0) * 2;
        int r4 = 64 + n + dk; if (r4 > 69) r4 = 69;  // discarded rows only
        bofs4[ks] = (r4 * SSTR + c0) * 2;
    }
    float* hps = hpart + ((b * 8 + bx) * 2 + (wv & 1)) * 112;
    short* gouts = locT + ((size_t)b * 512 + l0) * 112;

    __syncthreads();
    const bool edge = (bx == 0) || (bx == 7);

#define PASS3T(Ap, SRC, DST, BIAS, R0L, PL, E)                                   \
    if (wv == 0)      ctap<4,3,0,0,false,PL,false,E>(Ap,SRC,DST,nullptr,bofs,bofs4,BIAS,R0L,l0,hps,lane); \
    else if (wv == 1) ctap<4,2,0,3,true, PL,false,E>(Ap,SRC,DST,nullptr,bofs,bofs4,BIAS,R0L,l0,hps,lane); \
    else if (wv == 2) ctap<3,3,4,0,false,PL,false,E>(Ap,SRC,DST,nullptr,bofs,bofs4,BIAS,R0L,l0,hps,lane); \
    else              ctap<3,2,4,3,true, PL,false,E>(Ap,SRC,DST,nullptr,bofs,bofs4,BIAS,R0L,l0,hps,lane);

    if (edge) {
        PASS3T(A1, s_e, s_h, b1, l0 - 2, true, true)
        __syncthreads();
        PASS3T(A2, s_h, s_e, b2, l0 - 1, false, true)
    } else {
        PASS3T(A1, s_e, s_h, b1, l0 - 2, true, false)
        __syncthreads();
        PASS3T(A2, s_h, s_e, b2, l0 - 1, false, false)
    }
    __syncthreads();
    // li: outputs l in [l0, l0+63] always valid
    if (wv == 0)      ctap<4,2,0,0,false,false,true,false>(A3,s_e,nullptr,gouts,bofs,bofs4,b3,l0,l0,hps,lane);
    else if (wv == 1) ctap<4,2,0,2,false,false,true,false>(A3,s_e,nullptr,gouts,bofs,bofs4,b3,l0,l0,hps,lane);
    else if (wv == 2) ctap<3,2,4,0,false,false,true,false>(A3,s_e,nullptr,gouts,bofs,bofs4,b3,l0,l0,hps,lane);
    else              ctap<3,2,4,2,false,false,true,false>(A3,s_e,nullptr,gouts,bofs,bofs4,b3,l0,l0,hps,lane);
#undef PASS3T
}

// ---------------------------------------------------------------------------
// conv3 (1x1, loc half) + conv4 fused -> logits. 128-l tile; COLUMN-BAND
// tiling (measured neutral vs r0 split, simpler epilogue): each wave owns
// ALL 7 f-rows x 2 nt cols -> complete logits for its 32 columns, no
// cross-wave partial sum. r0 A-layout. LDS 128*SSTR*2 + 512 = 29696 B
// -> 5 blocks/CU.
// ---------------------------------------------------------------------------
template<int NTB>
DEV void c3tile(const short* s_in, float* s_part, const short* __restrict__ A4,
                const float* __restrict__ zg, const float* __restrict__ w4,
                int bb, int lane) {
    const int q = lane >> 4, n = lane & 15;
    const f32x4 z4 = {0.f, 0.f, 0.f, 0.f};
    f32x4 acc[7][2];
#pragma unroll
    for (int mt = 0; mt < 7; ++mt) {
        int fb = mt * 16 + q * 4;
        f32x4 zgv = *(const f32x4*)&zg[bb * 112 + fb];  // pad entries are 0
#pragma unroll
        for (int nt = 0; nt < 2; ++nt) acc[mt][nt] = zgv;
    }
#pragma unroll
    for (int ks = 0; ks < 4; ++ks) {
        short8 a[7];
#pragma unroll
        for (int mt = 0; mt < 7; ++mt)
            a[mt] = *(const short8*)&A4[(ks * 448 + mt * 64 + lane) * 8];
        int c0 = (ks * 4 + q) * 8;
        if (c0 > 104) c0 = 104;   // A zero for kappa>=100
        const char* bp = (const char*)(s_in + n * SSTR + c0);
        short8 bf[2];
#pragma unroll
        for (int nt = 0; nt < 2; ++nt)
            bf[nt] = *(const short8*)(bp + (NTB + nt) * ROWB);
#pragma unroll
        for (int mt = 0; mt < 7; ++mt)
#pragma unroll
            for (int nt = 0; nt < 2; ++nt)
                acc[mt][nt] = __builtin_amdgcn_mfma_f32_16x16x32_bf16(
                    a[mt], bf[nt], acc[mt][nt], 0, 0, 0);
    }
#pragma unroll
    for (int nt = 0; nt < 2; ++nt) {
        float part = 0.f;
#pragma unroll
        for (int mt = 0; mt < 7; ++mt) {
            const int fb = mt * 16 + q * 4;
            f32x4 w4v = (fb < 100) ? *(const f32x4*)&w4[fb] : z4;
#pragma unroll
            for (int r = 0; r < 4; ++r)
                part += fmaxf(acc[mt][nt][r], 0.f) * w4v[r];
        }
        part += __shfl_xor(part, 16, 64);
        part += __shfl_xor(part, 32, 64);
        if (q == 0) s_part[(NTB + nt) * 16 + n] = part;   // full logit
    }
}

__global__ __launch_bounds__(256, 5) void conv3_logits_kernel(
    const short* __restrict__ locT, const short* __restrict__ A4,
    const float* __restrict__ zg, const float* __restrict__ w4,
    const float* __restrict__ b4, float* __restrict__ logits) {
    extern __shared__ char smem[];
    short* s_in = (short*)smem;                       // [128][SSTR]
    float* s_part = (float*)(smem + 128 * SSTR * 2);  // [128]
    const int tid = threadIdx.x;
    const int b = blockIdx.y, l0r = blockIdx.x * 128;
    const int lane = tid & 63, wv = tid >> 6;

    {
        short8 tmp[8];
#pragma unroll
        for (int p = 0; p < 8; ++p) {
            int idx = tid + p * 256;
            int j = idx >> 4, c8 = idx & 15;
            if (c8 < 14)
                tmp[p] = *(const short8*)&locT[((size_t)b * 512 + l0r + j) * 112 + c8 * 8];
        }
#pragma unroll
        for (int p = 0; p < 8; ++p) {
            int idx = tid + p * 256;
            int j = idx >> 4, c8 = idx & 15;
            if (c8 < 14)
                *(short8*)&s_in[j * SSTR + c8 * 8] = tmp[p];
        }
    }
    __syncthreads();
    if (wv == 0)      c3tile<0>(s_in, s_part, A4, zg, w4, b, lane);
    else if (wv == 1) c3tile<2>(s_in, s_part, A4, zg, w4, b, lane);
    else if (wv == 2) c3tile<4>(s_in, s_part, A4, zg, w4, b, lane);
    else              c3tile<6>(s_in, s_part, A4, zg, w4, b, lane);
    __syncthreads();
    if (tid < 128)
        logits[b * 512 + l0r + tid] = s_part[tid] + b4[0];
}

// ---------------------------------------------------------------------------
// Finish pool: hm = sum over 16 wave-slot partials / 512, gate MLP, fold g:
// zg[b,f] = conv3_b[f] + sum_h g[b,h] * w3[f][h]   (f>=100 -> 0)
// ---------------------------------------------------------------------------
__global__ __launch_bounds__(128) void pool_gate_kernel(
    const float* __restrict__ hpart, const float* __restrict__ gi_w,
    const float* __restrict__ gi_b, const float* __restrict__ w3,
    const float* __restrict__ b3, float* __restrict__ zg) {
    int b = blockIdx.x, tid = threadIdx.x;
    __shared__ float s_hm[112];
    __shared__ float s_g[100];
    if (tid < 112) {
        float a = 0.f;
#pragma unroll
        for (int s = 0; s < 16; ++s) a += hpart[(b * 16 + s) * 112 + tid];
        s_hm[tid] = a * (1.f / 512.f);
    }
    __syncthreads();
    if (tid < 100) {
        float a = gi_b[tid];
        for (int f = 0; f < 100; ++f) a += s_hm[f] * gi_w[tid * 100 + f];
        s_g[tid] = fmaxf(a, 0.f);
    }
    __syncthreads();
    if (tid < 112) {
        float a = 0.f;
        if (tid < 100) {
            a = b3[tid];
            for (int h = 0; h < 100; ++h) a += s_g[h] * w3[tid * 200 + h];
        }
        zg[b * 112 + tid] = a;
    }
}

// ---------------------------------------------------------------------------
// Fused sampler + distil head, one block per b. Wave-parallel over k:
// wave wv handles k = wv, wv+4, wv+8 (<10) with wave-local shuffle softmax
// (no barriers inside the k loop). Merge via LDS max, then pooled gather
// (bf16 embT), fc1 relu, sigmoid head.
// ---------------------------------------------------------------------------
__global__ __launch_bounds__(256) void samp_head_kernel(
    const float* __restrict__ u, const float* __restrict__ logits,
    const int* __restrict__ xidx, const short* __restrict__ embT,
    const float* __restrict__ f1w, const float* __restrict__ f1b,
    const float* __restrict__ hw, const float* __restrict__ hb,
    float* __restrict__ cs_out, float* __restrict__ out) {
    const float EPSV = 1.1920929e-07f;
    const float INVT = 1.f / 0.3f;
    int b = blockIdx.x, tid = threadIdx.x;
    int lane = tid & 63, wv = tid >> 6;
    __shared__ float s_logT[512], s_cs[512];
    __shared__ int s_x[512];
    __shared__ float s_csw[4][512];
    __shared__ float s_acc[16][112];
    __shared__ float s_pool[112], s_h2[100], s_fin[4];
    for (int l = tid; l < 512; l += 256) {
        s_logT[l] = logits[b * 512 + l] * INVT;
        s_x[l] = xidx[b * 512 + l];
    }
    __syncthreads();
    // wave-local softmax per k
    const int nk = (wv < 2) ? 3 : 2;
    float csl[8];
#pragma unroll
    for (int i = 0; i < 8; ++i) csl[i] = 0.f;
    float lt[8];
#pragma unroll
    for (int i = 0; i < 8; ++i) lt[i] = s_logT[lane * 8 + i];
    for (int j = 0; j < nk; ++j) {
        int k = wv + 4 * j;
        f32x4 u0 = *(const f32x4*)&u[(b * 10 + k) * 512 + lane * 8];
        f32x4 u1 = *(const f32x4*)&u[(b * 10 + k) * 512 + lane * 8 + 4];
        float nz[8];
#pragma unroll
        for (int i = 0; i < 8; ++i) {
            float vv = (i < 4) ? u0[i] : u1[i - 4];
            vv = fminf(fmaxf(vv, EPSV), 1.f - EPSV);
            nz[i] = -__logf(-__logf(vv)) * INVT + lt[i];
        }
        float m = nz[0];
#pragma unroll
        for (int i = 1; i < 8; ++i) m = fmaxf(m, nz[i]);
#pragma unroll
        for (int off = 1; off <= 32; off <<= 1) m = fmaxf(m, __shfl_xor(m, off, 64));
        float e[8], s = 0.f;
#pragma unroll
        for (int i = 0; i < 8; ++i) { e[i] = __expf(nz[i] - m); s += e[i]; }
#pragma unroll
        for (int off = 1; off <= 32; off <<= 1) s += __shfl_xor(s, off, 64);
        float inv = 1.f / s;
#pragma unroll
        for (int i = 0; i < 8; ++i) csl[i] = fmaxf(csl[i], e[i] * inv);
    }
#pragma unroll
    for (int i = 0; i < 8; ++i) s_csw[wv][lane * 8 + i] = csl[i];
    __syncthreads();
    for (int l = tid; l < 512; l += 256) {
        float c = fmaxf(fmaxf(s_csw[0][l], s_csw[1][l]),
                        fmaxf(s_csw[2][l], s_csw[3][l]));
        s_cs[l] = c;
        cs_out[b * 512 + l] = c;
    }
    __syncthreads();
    // pooled partial sums: thread (jg, c8) covers l = jg+16t, channels c8*8..+7
    int jg = tid >> 4, c8 = tid & 15;
    if (c8 < 14) {
        f32x4 pa = {0.f, 0.f, 0.f, 0.f}, pb = {0.f, 0.f, 0.f, 0.f};
#pragma unroll 4
        for (int l = jg; l < 512; l += 16) {
            int row = s_x[l];
            float cv = s_cs[l];
            short8 e8 = *(const short8*)&embT[(size_t)row * 112 + c8 * 8];
#pragma unroll
            for (int r = 0; r < 4; ++r) {
                pa[r] += cv * bfu(e8[r]);
                pb[r] += cv * bfu(e8[4 + r]);
            }
        }
        *(f32x4*)&s_acc[jg][c8 * 8] = pa;
        *(f32x4*)&s_acc[jg][c8 * 8 + 4] = pb;
    }
    __syncthreads();
    if (tid < 112) {
        float p = 0.f;
#pragma unroll
        for (int g = 0; g < 16; ++g) p += s_acc[g][tid];
        s_pool[tid] = p * (1.f / 512.f);
    }
    __syncthreads();
    if (tid < 100) {
        float a = f1b[tid];
        for (int i = 0; i < 100; ++i) a += s_pool[i] * f1w[tid * 100 + i];
        s_h2[tid] = fmaxf(a, 0.f);
    }
    __syncthreads();
    float v = (tid < 100) ? s_h2[tid] * hw[tid] : 0.f;
#pragma unroll
    for (int off = 32; off >= 1; off >>= 1) v += __shfl_xor(v, off, 64);
    if (lane == 0) s_fin[wv] = v;
    __syncthreads();
    if (tid == 0) {
        float z = s_fin[0] + s_fin[1] + s_fin[2] + s_fin[3] + hb[0];
        out[b] = 1.f / (1.f + __expf(-z));
    }
}

// ---------------------------------------------------------------------------
extern "C" void kernel_launch(void* const* d_in, const int* in_sizes, int n_in,
                              void* d_out, int out_size, void* d_ws, size_t ws_size,
                              hipStream_t stream) {
    const int*   x   = (const int*)d_in[0];
    const float* u   = (const float*)d_in[1];
    const float* emb = (const float*)d_in[2];
    const float* c1w = (const float*)d_in[3];
    const float* c1b = (const float*)d_in[4];
    const float* giw = (const float*)d_in[5];
    const float* gib = (const float*)d_in[6];
    const float* c2w = (const float*)d_in[7];
    const float* c2b = (const float*)d_in[8];
    const float* liw = (const float*)d_in[9];
    const float* lib = (const float*)d_in[10];
    const float* c3w = (const float*)d_in[11];
    const float* c3b = (const float*)d_in[12];
    const float* c4w = (const float*)d_in[13];
    const float* c4b = (const float*)d_in[14];
    const float* f1w = (const float*)d_in[15];
    const float* f1b = (const float*)d_in[16];
    const float* hww = (const float*)d_in[17];
    const float* hbb = (const float*)d_in[18];
    float* out = (float*)d_out;

    char* ws = (char*)d_ws;
    short* locT   = (short*)(ws + 0);           // [512][512][112] bf16 (58.7 MB)
    short* embT   = (short*)(ws + 58720256);    // [100000][112] bf16 (22.4 MB)
    short* A1     = (short*)(ws + 81120256);    // 10*448*16 B each
    short* A2     = (short*)(ws + 81191936);
    short* A3     = (short*)(ws + 81263616);
    short* A4     = (short*)(ws + 81335296);    // 4*448*16 B
    float* zg     = (float*)(ws + 81363968);    // [512][112]
    float* logits = (float*)(ws + 81593344);    // [512][512]
    float* hpart  = (float*)(ws + 82641920);    // [512][8][2][112]

    emb_cvt_kernel<<<12500, 256, 0, stream>>>(emb, embT);
    pack_all_kernel<<<238, 64, 0, stream>>>(c1w, c2w, liw, c3w, A1, A2, A3, A4);

    size_t smemA = (size_t)2 * 70 * SSTR * 2;          // 31920 B -> 5 blocks/CU
    fused_conv_kernel<<<dim3(8, 512), 256, smemA, stream>>>(
        x, embT, A1, A2, A3, c1b, c2b, lib, locT, hpart);
    pool_gate_kernel<<<512, 128, 0, stream>>>(hpart, giw, gib, c3w, c3b, zg);
    size_t smemB = (size_t)128 * SSTR * 2 + 128 * 4;   // 29696 B -> 5 blocks/CU
    conv3_logits_kernel<<<dim3(4, 512), 256, smemB, stream>>>(
        locT, A4, zg, c4w, c4b, logits);
    samp_head_kernel<<<512, 256, 0, stream>>>(
        u, logits, x, embT, f1w, f1b, hww, hbb, out + 512, out);
}

// Round 5
// 341.093 us; speedup vs baseline: 2.9832x; 1.0498x over previous
//
#include <hip/hip_runtime.h>
#include <math.h>

#define DEV __device__ __forceinline__

typedef __attribute__((ext_vector_type(8))) short short8;
typedef __attribute__((ext_vector_type(4))) short short4v;
typedef __attribute__((ext_vector_type(4))) float f32x4;
typedef __attribute__((ext_vector_type(2))) unsigned uint2v;

// LDS row stride in shorts. 114 shorts = 57 words; gcd(57,32)=1 -> the
// 16-row B-read pattern spreads over all banks: SQ_LDS_BANK_CONFLICT
// measured 5.26M (SSTR=136) -> 0 (SSTR=114) in r4, correctness held
// (gfx950 tolerates the 4-mod-16 ds_read_b128 addresses this creates).
#define SSTR 114
#define ROWB (16 * SSTR * 2)   // bytes per 16-row tile

DEV short f2bf(float f) {
    unsigned u = __builtin_bit_cast(unsigned, f);
    unsigned r = (u + 0x7fffu + ((u >> 16) & 1u)) >> 16;
    return (short)r;
}

#if __has_builtin(__builtin_amdgcn_cvt_pk_bf16_f32)
DEV unsigned pk2bf(float a, float b) {
    auto v = __builtin_amdgcn_cvt_pk_bf16_f32(a, b);
    return __builtin_bit_cast(unsigned, v);
}
#else
DEV unsigned pk2bf(float a, float b) {
    return ((unsigned)(unsigned short)f2bf(a)) |
           (((unsigned)(unsigned short)f2bf(b)) << 16);
}
#endif

DEV float bfu(short s) {
    unsigned u = ((unsigned)(unsigned short)s) << 16;
    return __builtin_bit_cast(float, u);
}

// ---------------------------------------------------------------------------
// emb f32 [V][100] -> bf16 [V][112], cols 100..111 zeroed. 8 rows/block.
// ---------------------------------------------------------------------------
__global__ __launch_bounds__(256) void emb_cvt_kernel(
    const float* __restrict__ emb, short* __restrict__ embT) {
    int t = threadIdx.x;
    int row = blockIdx.x * 8 + (t >> 5);
    int c4 = t & 31;
    if (c4 >= 28) return;
    short4v v = {0, 0, 0, 0};
    if (c4 < 25) {
        f32x4 e = *(const f32x4*)&emb[row * 100 + c4 * 4];
#pragma unroll
        for (int r = 0; r < 4; ++r) v[r] = f2bf(e[r]);
    }
    *(short4v*)&embT[row * 112 + c4 * 4] = v;
}

// ---------------------------------------------------------------------------
// Pack conv weights into MFMA A-fragment order (r0-proven [ks][fblk][lane]
// layout: per (ks,mt) a wave's 64 lanes read one contiguous 1 KB line).
// mode 0 (3-tap): 13 octets per tap -> oct=kk>>3, dk=oct/13,
//   c=(oct-13*dk)*8+(kk&7); K = 320 (10 ks).
// mode 1 (conv3 loc half): kappa = c (cols 100..199 of w[100][200]), K 128.
// ---------------------------------------------------------------------------
__global__ __launch_bounds__(64) void pack_all_kernel(
    const float* __restrict__ c1w, const float* __restrict__ c2w,
    const float* __restrict__ liw, const float* __restrict__ c3w,
    short* __restrict__ A1, short* __restrict__ A2,
    short* __restrict__ A3, short* __restrict__ A4) {
    int bx = blockIdx.x;
    const float* w; short* dst; int mode, lbx;
    if (bx < 70)       { w = c1w; dst = A1; mode = 0; lbx = bx; }
    else if (bx < 140) { w = c2w; dst = A2; mode = 0; lbx = bx - 70; }
    else if (bx < 210) { w = liw; dst = A3; mode = 0; lbx = bx - 140; }
    else               { w = c3w; dst = A4; mode = 1; lbx = bx - 210; }
    int lane = threadIdx.x;
    int f = lbx % 7 * 16 + (lane & 15);
    int kb = (lbx / 7) * 32 + (lane >> 4) * 8;
    short8 v;
#pragma unroll
    for (int j = 0; j < 8; ++j) {
        int kk = kb + j;
        float val = 0.f;
        if (f < 100) {
            if (mode == 0) {
                int oct = kk >> 3, dk = oct / 13;
                int c = (oct - 13 * dk) * 8 + (kk & 7);
                if (dk < 3 && c < 100) val = w[(f * 100 + c) * 3 + dk];
            } else {
                if (kk < 100) val = w[f * 200 + 100 + kk];
            }
        }
        v[j] = f2bf(val);
    }
    *(short8*)&dst[(lbx * 64 + lane) * 8] = v;
}

// ---------------------------------------------------------------------------
// One 3-tap conv pass, BALANCED tile (r0-proven): this wave owns
// mt [MTB,MTB+MT) x nt [NTB,NTB+NT). B-reads amortize over MT MFMAs,
// A-rows over NT. Accumulator init = bias. CLAMPL: the nt==4 tile reads
// clamped rows (feeds only discarded outputs; halo chain loc<=63 -> c2<=65
// -> h<=67 -> e<=69 all real). EDGE: l-range zeroing only in bx 0/7.
// POOL: relu partial sums for l in [l0,l0+64) -> hpart_slot[112].
// ---------------------------------------------------------------------------
template<int MT, int NT, int MTB, int NTB, bool CLAMPL, bool POOL,
         bool TO_GLOBAL, bool EDGE>
DEV void ctap(const short* __restrict__ Ap, const short* s_src, short* s_dst,
              short* __restrict__ gout, const int* bofs, const int* bofs4,
              const float* __restrict__ bias, int row0l, int l0,
              float* __restrict__ hpart_slot, int lane) {
    const int q = lane >> 4, n = lane & 15;
    const f32x4 z4 = {0.f, 0.f, 0.f, 0.f};
    f32x4 acc[MT][NT];
#pragma unroll
    for (int mt = 0; mt < MT; ++mt) {
        int fb = (MTB + mt) * 16 + q * 4;
        f32x4 bs = (fb < 100) ? *(const f32x4*)&bias[fb] : z4;
#pragma unroll
        for (int nt = 0; nt < NT; ++nt) acc[mt][nt] = bs;
    }
#pragma unroll
    for (int ks = 0; ks < 10; ++ks) {
        short8 a[MT];
#pragma unroll
        for (int mt = 0; mt < MT; ++mt)
            a[mt] = *(const short8*)&Ap[(ks * 448 + (MTB + mt) * 64 + lane) * 8];
        const char* bp = (const char*)s_src + bofs[ks];
        short8 bf[NT];
#pragma unroll
        for (int nt = 0; nt < NT; ++nt) {
            if (CLAMPL && (NTB + nt) == 4)
                bf[nt] = *(const short8*)((const char*)s_src + bofs4[ks]);
            else
                bf[nt] = *(const short8*)(bp + (NTB + nt) * ROWB);
        }
#pragma unroll
        for (int mt = 0; mt < MT; ++mt)
#pragma unroll
            for (int nt = 0; nt < NT; ++nt)
                acc[mt][nt] = __builtin_amdgcn_mfma_f32_16x16x32_bf16(
                    a[mt], bf[nt], acc[mt][nt], 0, 0, 0);
    }
    f32x4 ps[MT];
    if constexpr (POOL) {
#pragma unroll
        for (int mt = 0; mt < MT; ++mt) ps[mt] = z4;
    }
#pragma unroll
    for (int nt = 0; nt < NT; ++nt) {
        const int j = (NTB + nt) * 16 + n;
        const int l = row0l + j;
        bool lok = true;
        if constexpr (EDGE) lok = ((unsigned)l < 512u);
        const bool pok = POOL && (l >= l0) && (l < l0 + 64);
#pragma unroll
        for (int mt = 0; mt < MT; ++mt) {
            const int fb = (MTB + mt) * 16 + q * 4;
            f32x4 v;
#pragma unroll
            for (int r = 0; r < 4; ++r) {
                v[r] = fmaxf(acc[mt][nt][r], 0.f);
                if constexpr (EDGE) v[r] = lok ? v[r] : 0.f;
            }
            if constexpr (POOL) {
                if (pok) {
#pragma unroll
                    for (int r = 0; r < 4; ++r) ps[mt][r] += v[r];
                }
            }
            uint2v pk;
            pk[0] = pk2bf(v[0], v[1]); pk[1] = pk2bf(v[2], v[3]);
            if constexpr (TO_GLOBAL) {
                *(uint2v*)&gout[j * 112 + fb] = pk;
            } else {
                if ((NTB + nt) < 4 || n < 6)      // store rows j < 70 only
                    *(uint2v*)&s_dst[j * SSTR + fb] = pk;
            }
        }
    }
    if constexpr (POOL) {
#pragma unroll
        for (int mt = 0; mt < MT; ++mt)
#pragma unroll
            for (int off = 1; off <= 8; off <<= 1)
#pragma unroll
                for (int r = 0; r < 4; ++r)
                    ps[mt][r] += __shfl_xor(ps[mt][r], off, 64);
        if (n == 0) {
#pragma unroll
            for (int mt = 0; mt < MT; ++mt)
                *(f32x4*)&hpart_slot[(MTB + mt) * 16 + q * 4] = ps[mt];
        }
    }
}

// ---------------------------------------------------------------------------
// Fused conv1 -> conv2 -> li, 64-wide l-tile, 256 threads (4 waves), grid
// (8,512) -- the r0-proven structure. Staging = VGPR gather + ds_write
// (global_load_lds with scattered sources serializes the LDS-DMA: measured
// 3.6x regression in r2). Balanced wave tiles: wv0=(4,3)@(0,0) wv1=(4,2)@(0,3)
// wv2=(3,3)@(4,0) wv3=(3,2)@(4,3); li: NT=2 each @(0/4, 0/2).
// launch_bounds min-waves=4: this kernel needs ~64 VGPR + 64 AGPR = 128
// total regs/wave on the unified file -> 4 waves/SIMD is the reg-file
// ceiling; requesting 5 (r4) forced ~100 B/thread scratch spill (+105 MB
// HBM writes, dur 116->199 us). LDS 2*70*SSTR*2 = 31920 B.
// ---------------------------------------------------------------------------
__global__ __launch_bounds__(256, 4) void fused_conv_kernel(
    const int* __restrict__ xidx, const short* __restrict__ embT,
    const short* __restrict__ A1, const short* __restrict__ A2,
    const short* __restrict__ A3,
    const float* __restrict__ b1, const float* __restrict__ b2,
    const float* __restrict__ b3,
    short* __restrict__ locT, float* __restrict__ hpart) {
    extern __shared__ char smem[];
    short* s_e = (short*)smem;                    // [70][SSTR], later c2
    short* s_h = (short*)(smem + 70 * SSTR * 2);  // [70][SSTR]
    const int tid = threadIdx.x;
    const int b = blockIdx.y, bx = blockIdx.x, l0 = bx * 64;
    const int lane = tid & 63, wv = tid >> 6;
    const int q = lane >> 4, n = lane & 15;

    // stage e: 70 rows x 14 b128 chunks (virtual 16-grid; c8>=14 skipped)
#pragma unroll
    for (int p = 0; p < 5; ++p) {
        int idx = tid + p * 256;           // 0..1279, need j<70
        int j = idx >> 4, c8 = idx & 15;
        if (j < 70 && c8 < 14) {
            int lg = l0 - 3 + j;
            short8 v = {0, 0, 0, 0, 0, 0, 0, 0};
            if (lg >= 0 && lg < 512) {
                int row = xidx[b * 512 + lg];
                v = *(const short8*)&embT[row * 112 + c8 * 8];
            }
            *(short8*)&s_e[j * SSTR + c8 * 8] = v;
        }
    }

    // per-lane B byte offsets for all 10 k-steps (row n+dk, col c0)
    int bofs[10], bofs4[10];
#pragma unroll
    for (int ks = 0; ks < 10; ++ks) {
        int oct = ks * 4 + q;
        int dk = (oct >= 39) ? 3 : (oct >= 26) ? 2 : (oct >= 13) ? 1 : 0;
        int c0 = (oct - 13 * dk) * 8;
        bofs[ks] = ((n + dk) * SSTR + c0) * 2;
        int r4 = 64 + n + dk; if (r4 > 69) r4 = 69;  // discarded rows only
        bofs4[ks] = (r4 * SSTR + c0) * 2;
    }
    float* hps = hpart + ((b * 8 + bx) * 2 + (wv & 1)) * 112;
    short* gouts = locT + ((size_t)b * 512 + l0) * 112;

    __syncthreads();
    const bool edge = (bx == 0) || (bx == 7);

#define PASS3T(Ap, SRC, DST, BIAS, R0L, PL, E)                                   \
    if (wv == 0)      ctap<4,3,0,0,false,PL,false,E>(Ap,SRC,DST,nullptr,bofs,bofs4,BIAS,R0L,l0,hps,lane); \
    else if (wv == 1) ctap<4,2,0,3,true, PL,false,E>(Ap,SRC,DST,nullptr,bofs,bofs4,BIAS,R0L,l0,hps,lane); \
    else if (wv == 2) ctap<3,3,4,0,false,PL,false,E>(Ap,SRC,DST,nullptr,bofs,bofs4,BIAS,R0L,l0,hps,lane); \
    else              ctap<3,2,4,3,true, PL,false,E>(Ap,SRC,DST,nullptr,bofs,bofs4,BIAS,R0L,l0,hps,lane);

    if (edge) {
        PASS3T(A1, s_e, s_h, b1, l0 - 2, true, true)
        __syncthreads();
        PASS3T(A2, s_h, s_e, b2, l0 - 1, false, true)
    } else {
        PASS3T(A1, s_e, s_h, b1, l0 - 2, true, false)
        __syncthreads();
        PASS3T(A2, s_h, s_e, b2, l0 - 1, false, false)
    }
    __syncthreads();
    // li: outputs l in [l0, l0+63] always valid
    if (wv == 0)      ctap<4,2,0,0,false,false,true,false>(A3,s_e,nullptr,gouts,bofs,bofs4,b3,l0,l0,hps,lane);
    else if (wv == 1) ctap<4,2,0,2,false,false,true,false>(A3,s_e,nullptr,gouts,bofs,bofs4,b3,l0,l0,hps,lane);
    else if (wv == 2) ctap<3,2,4,0,false,false,true,false>(A3,s_e,nullptr,gouts,bofs,bofs4,b3,l0,l0,hps,lane);
    else              ctap<3,2,4,2,false,false,true,false>(A3,s_e,nullptr,gouts,bofs,bofs4,b3,l0,l0,hps,lane);
#undef PASS3T
}

// ---------------------------------------------------------------------------
// conv3 (1x1, loc half) + conv4 fused -> logits. 128-l tile; COLUMN-BAND
// tiling (r3 decomposition showed it neutral vs the r0 split, with a
// simpler epilogue): each wave owns ALL 7 f-rows x 2 nt cols -> complete
// logits for its 32 columns, no cross-wave partial sum. r0 A-layout.
// LDS 128*SSTR*2 + 512 = 29696 B; launch_bounds min-waves=4 (reg ceiling:
// acc[7][2] = 56 AGPRs + working VGPRs).
// ---------------------------------------------------------------------------
template<int NTB>
DEV void c3tile(const short* s_in, float* s_part, const short* __restrict__ A4,
                const float* __restrict__ zg, const float* __restrict__ w4,
                int bb, int lane) {
    const int q = lane >> 4, n = lane & 15;
    const f32x4 z4 = {0.f, 0.f, 0.f, 0.f};
    f32x4 acc[7][2];
#pragma unroll
    for (int mt = 0; mt < 7; ++mt) {
        int fb = mt * 16 + q * 4;
        f32x4 zgv = *(const f32x4*)&zg[bb * 112 + fb];  // pad entries are 0
#pragma unroll
        for (int nt = 0; nt < 2; ++nt) acc[mt][nt] = zgv;
    }
#pragma unroll
    for (int ks = 0; ks < 4; ++ks) {
        short8 a[7];
#pragma unroll
        for (int mt = 0; mt < 7; ++mt)
            a[mt] = *(const short8*)&A4[(ks * 448 + mt * 64 + lane) * 8];
        int c0 = (ks * 4 + q) * 8;
        if (c0 > 104) c0 = 104;   // A zero for kappa>=100
        const char* bp = (const char*)(s_in + n * SSTR + c0);
        short8 bf[2];
#pragma unroll
        for (int nt = 0; nt < 2; ++nt)
            bf[nt] = *(const short8*)(bp + (NTB + nt) * ROWB);
#pragma unroll
        for (int mt = 0; mt < 7; ++mt)
#pragma unroll
            for (int nt = 0; nt < 2; ++nt)
                acc[mt][nt] = __builtin_amdgcn_mfma_f32_16x16x32_bf16(
                    a[mt], bf[nt], acc[mt][nt], 0, 0, 0);
    }
#pragma unroll
    for (int nt = 0; nt < 2; ++nt) {
        float part = 0.f;
#pragma unroll
        for (int mt = 0; mt < 7; ++mt) {
            const int fb = mt * 16 + q * 4;
            f32x4 w4v = (fb < 100) ? *(const f32x4*)&w4[fb] : z4;
#pragma unroll
            for (int r = 0; r < 4; ++r)
                part += fmaxf(acc[mt][nt][r], 0.f) * w4v[r];
        }
        part += __shfl_xor(part, 16, 64);
        part += __shfl_xor(part, 32, 64);
        if (q == 0) s_part[(NTB + nt) * 16 + n] = part;   // full logit
    }
}

__global__ __launch_bounds__(256, 4) void conv3_logits_kernel(
    const short* __restrict__ locT, const short* __restrict__ A4,
    const float* __restrict__ zg, const float* __restrict__ w4,
    const float* __restrict__ b4, float* __restrict__ logits) {
    extern __shared__ char smem[];
    short* s_in = (short*)smem;                       // [128][SSTR]
    float* s_part = (float*)(smem + 128 * SSTR * 2);  // [128]
    const int tid = threadIdx.x;
    const int b = blockIdx.y, l0r = blockIdx.x * 128;
    const int lane = tid & 63, wv = tid >> 6;

    {
        short8 tmp[8];
#pragma unroll
        for (int p = 0; p < 8; ++p) {
            int idx = tid + p * 256;
            int j = idx >> 4, c8 = idx & 15;
            if (c8 < 14)
                tmp[p] = *(const short8*)&locT[((size_t)b * 512 + l0r + j) * 112 + c8 * 8];
        }
#pragma unroll
        for (int p = 0; p < 8; ++p) {
            int idx = tid + p * 256;
            int j = idx >> 4, c8 = idx & 15;
            if (c8 < 14)
                *(short8*)&s_in[j * SSTR + c8 * 8] = tmp[p];
        }
    }
    __syncthreads();
    if (wv == 0)      c3tile<0>(s_in, s_part, A4, zg, w4, b, lane);
    else if (wv == 1) c3tile<2>(s_in, s_part, A4, zg, w4, b, lane);
    else if (wv == 2) c3tile<4>(s_in, s_part, A4, zg, w4, b, lane);
    else              c3tile<6>(s_in, s_part, A4, zg, w4, b, lane);
    __syncthreads();
    if (tid < 128)
        logits[b * 512 + l0r + tid] = s_part[tid] + b4[0];
}

// ---------------------------------------------------------------------------
// Finish pool: hm = sum over 16 wave-slot partials / 512, gate MLP, fold g:
// zg[b,f] = conv3_b[f] + sum_h g[b,h] * w3[f][h]   (f>=100 -> 0)
// ---------------------------------------------------------------------------
__global__ __launch_bounds__(128) void pool_gate_kernel(
    const float* __restrict__ hpart, const float* __restrict__ gi_w,
    const float* __restrict__ gi_b, const float* __restrict__ w3,
    const float* __restrict__ b3, float* __restrict__ zg) {
    int b = blockIdx.x, tid = threadIdx.x;
    __shared__ float s_hm[112];
    __shared__ float s_g[100];
    if (tid < 112) {
        float a = 0.f;
#pragma unroll
        for (int s = 0; s < 16; ++s) a += hpart[(b * 16 + s) * 112 + tid];
        s_hm[tid] = a * (1.f / 512.f);
    }
    __syncthreads();
    if (tid < 100) {
        float a = gi_b[tid];
        for (int f = 0; f < 100; ++f) a += s_hm[f] * gi_w[tid * 100 + f];
        s_g[tid] = fmaxf(a, 0.f);
    }
    __syncthreads();
    if (tid < 112) {
        float a = 0.f;
        if (tid < 100) {
            a = b3[tid];
            for (int h = 0; h < 100; ++h) a += s_g[h] * w3[tid * 200 + h];
        }
        zg[b * 112 + tid] = a;
    }
}

// ---------------------------------------------------------------------------
// Fused sampler + distil head, one block per b. Wave-parallel over k:
// wave wv handles k = wv, wv+4, wv+8 (<10) with wave-local shuffle softmax
// (no barriers inside the k loop). Merge via LDS max, then pooled gather
// (bf16 embT), fc1 relu, sigmoid head.
// ---------------------------------------------------------------------------
__global__ __launch_bounds__(256) void samp_head_kernel(
    const float* __restrict__ u, const float* __restrict__ logits,
    const int* __restrict__ xidx, const short* __restrict__ embT,
    const float* __restrict__ f1w, const float* __restrict__ f1b,
    const float* __restrict__ hw, const float* __restrict__ hb,
    float* __restrict__ cs_out, float* __restrict__ out) {
    const float EPSV = 1.1920929e-07f;
    const float INVT = 1.f / 0.3f;
    int b = blockIdx.x, tid = threadIdx.x;
    int lane = tid & 63, wv = tid >> 6;
    __shared__ float s_logT[512], s_cs[512];
    __shared__ int s_x[512];
    __shared__ float s_csw[4][512];
    __shared__ float s_acc[16][112];
    __shared__ float s_pool[112], s_h2[100], s_fin[4];
    for (int l = tid; l < 512; l += 256) {
        s_logT[l] = logits[b * 512 + l] * INVT;
        s_x[l] = xidx[b * 512 + l];
    }
    __syncthreads();
    // wave-local softmax per k
    const int nk = (wv < 2) ? 3 : 2;
    float csl[8];
#pragma unroll
    for (int i = 0; i < 8; ++i) csl[i] = 0.f;
    float lt[8];
#pragma unroll
    for (int i = 0; i < 8; ++i) lt[i] = s_logT[lane * 8 + i];
    for (int j = 0; j < nk; ++j) {
        int k = wv + 4 * j;
        f32x4 u0 = *(const f32x4*)&u[(b * 10 + k) * 512 + lane * 8];
        f32x4 u1 = *(const f32x4*)&u[(b * 10 + k) * 512 + lane * 8 + 4];
        float nz[8];
#pragma unroll
        for (int i = 0; i < 8; ++i) {
            float vv = (i < 4) ? u0[i] : u1[i - 4];
            vv = fminf(fmaxf(vv, EPSV), 1.f - EPSV);
            nz[i] = -__logf(-__logf(vv)) * INVT + lt[i];
        }
        float m = nz[0];
#pragma unroll
        for (int i = 1; i < 8; ++i) m = fmaxf(m, nz[i]);
#pragma unroll
        for (int off = 1; off <= 32; off <<= 1) m = fmaxf(m, __shfl_xor(m, off, 64));
        float e[8], s = 0.f;
#pragma unroll
        for (int i = 0; i < 8; ++i) { e[i] = __expf(nz[i] - m); s += e[i]; }
#pragma unroll
        for (int off = 1; off <= 32; off <<= 1) s += __shfl_xor(s, off, 64);
        float inv = 1.f / s;
#pragma unroll
        for (int i = 0; i < 8; ++i) csl[i] = fmaxf(csl[i], e[i] * inv);
    }
#pragma unroll
    for (int i = 0; i < 8; ++i) s_csw[wv][lane * 8 + i] = csl[i];
    __syncthreads();
    for (int l = tid; l < 512; l += 256) {
        float c = fmaxf(fmaxf(s_csw[0][l], s_csw[1][l]),
                        fmaxf(s_csw[2][l], s_csw[3][l]));
        s_cs[l] = c;
        cs_out[b * 512 + l] = c;
    }
    __syncthreads();
    // pooled partial sums: thread (jg, c8) covers l = jg+16t, channels c8*8..+7
    int jg = tid >> 4, c8 = tid & 15;
    if (c8 < 14) {
        f32x4 pa = {0.f, 0.f, 0.f, 0.f}, pb = {0.f, 0.f, 0.f, 0.f};
#pragma unroll 4
        for (int l = jg; l < 512; l += 16) {
            int row = s_x[l];
            float cv = s_cs[l];
            short8 e8 = *(const short8*)&embT[(size_t)row * 112 + c8 * 8];
#pragma unroll
            for (int r = 0; r < 4; ++r) {
                pa[r] += cv * bfu(e8[r]);
                pb[r] += cv * bfu(e8[4 + r]);
            }
        }
        *(f32x4*)&s_acc[jg][c8 * 8] = pa;
        *(f32x4*)&s_acc[jg][c8 * 8 + 4] = pb;
    }
    __syncthreads();
    if (tid < 112) {
        float p = 0.f;
#pragma unroll
        for (int g = 0; g < 16; ++g) p += s_acc[g][tid];
        s_pool[tid] = p * (1.f / 512.f);
    }
    __syncthreads();
    if (tid < 100) {
        float a = f1b[tid];
        for (int i = 0; i < 100; ++i) a += s_pool[i] * f1w[tid * 100 + i];
        s_h2[tid] = fmaxf(a, 0.f);
    }
    __syncthreads();
    float v = (tid < 100) ? s_h2[tid] * hw[tid] : 0.f;
#pragma unroll
    for (int off = 32; off >= 1; off >>= 1) v += __shfl_xor(v, off, 64);
    if (lane == 0) s_fin[wv] = v;
    __syncthreads();
    if (tid == 0) {
        float z = s_fin[0] + s_fin[1] + s_fin[2] + s_fin[3] + hb[0];
        out[b] = 1.f / (1.f + __expf(-z));
    }
}

// ---------------------------------------------------------------------------
extern "C" void kernel_launch(void* const* d_in, const int* in_sizes, int n_in,
                              void* d_out, int out_size, void* d_ws, size_t ws_size,
                              hipStream_t stream) {
    const int*   x   = (const int*)d_in[0];
    const float* u   = (const float*)d_in[1];
    const float* emb = (const float*)d_in[2];
    const float* c1w = (const float*)d_in[3];
    const float* c1b = (const float*)d_in[4];
    const float* giw = (const float*)d_in[5];
    const float* gib = (const float*)d_in[6];
    const float* c2w = (const float*)d_in[7];
    const float* c2b = (const float*)d_in[8];
    const float* liw = (const float*)d_in[9];
    const float* lib = (const float*)d_in[10];
    const float* c3w = (const float*)d_in[11];
    const float* c3b = (const float*)d_in[12];
    const float* c4w = (const float*)d_in[13];
    const float* c4b = (const float*)d_in[14];
    const float* f1w = (const float*)d_in[15];
    const float* f1b = (const float*)d_in[16];
    const float* hww = (const float*)d_in[17];
    const float* hbb = (const float*)d_in[18];
    float* out = (float*)d_out;

    char* ws = (char*)d_ws;
    short* locT   = (short*)(ws + 0);           // [512][512][112] bf16 (58.7 MB)
    short* embT   = (short*)(ws + 58720256);    // [100000][112] bf16 (22.4 MB)
    short* A1     = (short*)(ws + 81120256);    // 10*448*16 B each
    short* A2     = (short*)(ws + 81191936);
    short* A3     = (short*)(ws + 81263616);
    short* A4     = (short*)(ws + 81335296);    // 4*448*16 B
    float* zg     = (float*)(ws + 81363968);    // [512][112]
    float* logits = (float*)(ws + 81593344);    // [512][512]
    float* hpart  = (float*)(ws + 82641920);    // [512][8][2][112]

    emb_cvt_kernel<<<12500, 256, 0, stream>>>(emb, embT);
    pack_all_kernel<<<238, 64, 0, stream>>>(c1w, c2w, liw, c3w, A1, A2, A3, A4);

    size_t smemA = (size_t)2 * 70 * SSTR * 2;          // 31920 B
    fused_conv_kernel<<<dim3(8, 512), 256, smemA, stream>>>(
        x, embT, A1, A2, A3, c1b, c2b, lib, locT, hpart);
    pool_gate_kernel<<<512, 128, 0, stream>>>(hpart, giw, gib, c3w, c3b, zg);
    size_t smemB = (size_t)128 * SSTR * 2 + 128 * 4;   // 29696 B
    conv3_logits_kernel<<<dim3(4, 512), 256, smemB, stream>>>(
        locT, A4, zg, c4w, c4b, logits);
    samp_head_kernel<<<512, 256, 0, stream>>>(
        u, logits, x, embT, f1w, f1b, hww, hbb, out + 512, out);
}

// Round 6
// 263.534 us; speedup vs baseline: 3.8612x; 1.2943x over previous
//
#include <hip/hip_runtime.h>
#include <math.h>

#define DEV __device__ __forceinline__

typedef __attribute__((ext_vector_type(8))) short short8;
typedef __attribute__((ext_vector_type(4))) short short4v;
typedef __attribute__((ext_vector_type(4))) float f32x4;
typedef __attribute__((ext_vector_type(2))) unsigned uint2v;

// LDS row stride in shorts (272 B = 68 words; 68 mod 32 = 4 -> b128 reads
// land 2-way on banks = free per m136). MUST be a multiple of 8 shorts:
// SSTR=114 (r4/r5) gave 4-mod-16 ds_*_b128 addresses -- correct results but
// ~60% LDS-throughput penalty (116 -> 187 us) with conflicts reading 0.
#define SSTR 136
#define ROWB (16 * SSTR * 2)   // 4352 B per 16-row tile

DEV short f2bf(float f) {
    unsigned u = __builtin_bit_cast(unsigned, f);
    unsigned r = (u + 0x7fffu + ((u >> 16) & 1u)) >> 16;
    return (short)r;
}

#if __has_builtin(__builtin_amdgcn_cvt_pk_bf16_f32)
DEV unsigned pk2bf(float a, float b) {
    auto v = __builtin_amdgcn_cvt_pk_bf16_f32(a, b);
    return __builtin_bit_cast(unsigned, v);
}
#else
DEV unsigned pk2bf(float a, float b) {
    return ((unsigned)(unsigned short)f2bf(a)) |
           (((unsigned)(unsigned short)f2bf(b)) << 16);
}
#endif

DEV float bfu(short s) {
    unsigned u = ((unsigned)(unsigned short)s) << 16;
    return __builtin_bit_cast(float, u);
}

// ---------------------------------------------------------------------------
// prep: blocks 0..12499 = emb cvt (f32 [V][100] -> bf16 [V][112], pad cols
// zeroed, 8 rows/block); blocks 12500.. = weight packing into MFMA A-frag
// order ([ks][fblk][lane] layout: per (ks,mt) a wave reads one contiguous
// 1 KB line). Merged to save one launch.
// ---------------------------------------------------------------------------
__global__ __launch_bounds__(256) void prep_kernel(
    const float* __restrict__ emb, short* __restrict__ embT,
    const float* __restrict__ c1w, const float* __restrict__ c2w,
    const float* __restrict__ liw, const float* __restrict__ c3w,
    short* __restrict__ A1, short* __restrict__ A2,
    short* __restrict__ A3, short* __restrict__ A4) {
    int bxg = blockIdx.x;
    if (bxg < 12500) {
        int t = threadIdx.x;
        int row = bxg * 8 + (t >> 5);
        int c4 = t & 31;
        if (c4 >= 28) return;
        short4v v = {0, 0, 0, 0};
        if (c4 < 25) {
            f32x4 e = *(const f32x4*)&emb[row * 100 + c4 * 4];
#pragma unroll
            for (int r = 0; r < 4; ++r) v[r] = f2bf(e[r]);
        }
        *(short4v*)&embT[row * 112 + c4 * 4] = v;
        return;
    }
    if (threadIdx.x >= 64) return;
    int bx = bxg - 12500;
    const float* w; short* dst; int mode, lbx;
    if (bx < 70)       { w = c1w; dst = A1; mode = 0; lbx = bx; }
    else if (bx < 140) { w = c2w; dst = A2; mode = 0; lbx = bx - 70; }
    else if (bx < 210) { w = liw; dst = A3; mode = 0; lbx = bx - 140; }
    else               { w = c3w; dst = A4; mode = 1; lbx = bx - 210; }
    int lane = threadIdx.x;
    int f = lbx % 7 * 16 + (lane & 15);
    int kb = (lbx / 7) * 32 + (lane >> 4) * 8;
    short8 v;
#pragma unroll
    for (int j = 0; j < 8; ++j) {
        int kk = kb + j;
        float val = 0.f;
        if (f < 100) {
            if (mode == 0) {
                int oct = kk >> 3, dk = oct / 13;
                int c = (oct - 13 * dk) * 8 + (kk & 7);
                if (dk < 3 && c < 100) val = w[(f * 100 + c) * 3 + dk];
            } else {
                if (kk < 100) val = w[f * 200 + 100 + kk];
            }
        }
        v[j] = f2bf(val);
    }
    *(short8*)&dst[(lbx * 64 + lane) * 8] = v;
}

// ---------------------------------------------------------------------------
// One 3-tap conv pass, BALANCED tile (r0-proven): this wave owns mt
// [MTB,MTB+MT) x nt [NTB,NTB+NT). B-reads amortize over MT MFMAs, A-rows
// over NT. Accumulator init = bias. CLAMPL: the nt==4 tile reads clamped
// rows (feeds only discarded outputs; halo chain loc<=63 -> c2<=65 ->
// h<=67 -> e<=69 all real). EDGE: l-range zeroing only in bx 0/7.
// POOL: relu partial sums for l in [l0,l0+64) -> hpart_slot[112].
// ---------------------------------------------------------------------------
template<int MT, int NT, int MTB, int NTB, bool CLAMPL, bool POOL,
         bool TO_GLOBAL, bool EDGE>
DEV void ctap(const short* __restrict__ Ap, const short* s_src, short* s_dst,
              short* __restrict__ gout, const int* bofs, const int* bofs4,
              const float* __restrict__ bias, int row0l, int l0,
              float* __restrict__ hpart_slot, int lane) {
    const int q = lane >> 4, n = lane & 15;
    const f32x4 z4 = {0.f, 0.f, 0.f, 0.f};
    f32x4 acc[MT][NT];
#pragma unroll
    for (int mt = 0; mt < MT; ++mt) {
        int fb = (MTB + mt) * 16 + q * 4;
        f32x4 bs = (fb < 100) ? *(const f32x4*)&bias[fb] : z4;
#pragma unroll
        for (int nt = 0; nt < NT; ++nt) acc[mt][nt] = bs;
    }
#pragma unroll
    for (int ks = 0; ks < 10; ++ks) {
        short8 a[MT];
#pragma unroll
        for (int mt = 0; mt < MT; ++mt)
            a[mt] = *(const short8*)&Ap[(ks * 448 + (MTB + mt) * 64 + lane) * 8];
        const char* bp = (const char*)s_src + bofs[ks];
        short8 bf[NT];
#pragma unroll
        for (int nt = 0; nt < NT; ++nt) {
            if (CLAMPL && (NTB + nt) == 4)
                bf[nt] = *(const short8*)((const char*)s_src + bofs4[ks]);
            else
                bf[nt] = *(const short8*)(bp + (NTB + nt) * ROWB);
        }
#pragma unroll
        for (int mt = 0; mt < MT; ++mt)
#pragma unroll
            for (int nt = 0; nt < NT; ++nt)
                acc[mt][nt] = __builtin_amdgcn_mfma_f32_16x16x32_bf16(
                    a[mt], bf[nt], acc[mt][nt], 0, 0, 0);
    }
    f32x4 ps[MT];
    if constexpr (POOL) {
#pragma unroll
        for (int mt = 0; mt < MT; ++mt) ps[mt] = z4;
    }
#pragma unroll
    for (int nt = 0; nt < NT; ++nt) {
        const int j = (NTB + nt) * 16 + n;
        const int l = row0l + j;
        bool lok = true;
        if constexpr (EDGE) lok = ((unsigned)l < 512u);
        const bool pok = POOL && (l >= l0) && (l < l0 + 64);
#pragma unroll
        for (int mt = 0; mt < MT; ++mt) {
            const int fb = (MTB + mt) * 16 + q * 4;
            f32x4 v;
#pragma unroll
            for (int r = 0; r < 4; ++r) {
                v[r] = fmaxf(acc[mt][nt][r], 0.f);
                if constexpr (EDGE) v[r] = lok ? v[r] : 0.f;
            }
            if constexpr (POOL) {
                if (pok) {
#pragma unroll
                    for (int r = 0; r < 4; ++r) ps[mt][r] += v[r];
                }
            }
            uint2v pk;
            pk[0] = pk2bf(v[0], v[1]); pk[1] = pk2bf(v[2], v[3]);
            if constexpr (TO_GLOBAL) {
                *(uint2v*)&gout[j * 112 + fb] = pk;
            } else {
                if ((NTB + nt) < 4 || n < 6)      // store rows j < 70 only
                    *(uint2v*)&s_dst[j * SSTR + fb] = pk;
            }
        }
    }
    if constexpr (POOL) {
#pragma unroll
        for (int mt = 0; mt < MT; ++mt)
#pragma unroll
            for (int off = 1; off <= 8; off <<= 1)
#pragma unroll
                for (int r = 0; r < 4; ++r)
                    ps[mt][r] += __shfl_xor(ps[mt][r], off, 64);
        if (n == 0) {
#pragma unroll
            for (int mt = 0; mt < MT; ++mt)
                *(f32x4*)&hpart_slot[(MTB + mt) * 16 + q * 4] = ps[mt];
        }
    }
}

// ---------------------------------------------------------------------------
// Fused conv1 -> conv2 -> li, 64-wide l-tile, 256 threads (4 waves), grid
// (8,512) -- byte-exact r0 (116 us, the proven optimum). Staging = VGPR
// gather + ds_write (global_load_lds with scattered sources serializes the
// LDS-DMA: 3.6x regression, r2). Balanced wave tiles: wv0=(4,3)@(0,0)
// wv1=(4,2)@(0,3) wv2=(3,3)@(4,0) wv3=(3,2)@(4,3); li: NT=2 each @(0/4,0/2).
// Reg budget ~64 VGPR + 64 AGPR = 128/wave -> 4 waves/SIMD is the ceiling
// (min-waves=5 spilled ~100 B/thread, r4). LDS 2*72*SSTR*2 = 39168 B.
// ---------------------------------------------------------------------------
__global__ __launch_bounds__(256, 4) void fused_conv_kernel(
    const int* __restrict__ xidx, const short* __restrict__ embT,
    const short* __restrict__ A1, const short* __restrict__ A2,
    const short* __restrict__ A3,
    const float* __restrict__ b1, const float* __restrict__ b2,
    const float* __restrict__ b3,
    short* __restrict__ locT, float* __restrict__ hpart) {
    extern __shared__ char smem[];
    short* s_e = (short*)smem;                    // [72][SSTR], later c2
    short* s_h = (short*)(smem + 72 * SSTR * 2);  // [72][SSTR]
    const int tid = threadIdx.x;
    const int b = blockIdx.y, bx = blockIdx.x, l0 = bx * 64;
    const int lane = tid & 63, wv = tid >> 6;
    const int q = lane >> 4, n = lane & 15;

    // stage e: 70 rows x 14 b128 chunks (virtual 16-grid; c8>=14 skipped)
#pragma unroll
    for (int p = 0; p < 5; ++p) {
        int idx = tid + p * 256;           // 0..1279, need j<70
        int j = idx >> 4, c8 = idx & 15;
        if (j < 70 && c8 < 14) {
            int lg = l0 - 3 + j;
            short8 v = {0, 0, 0, 0, 0, 0, 0, 0};
            if (lg >= 0 && lg < 512) {
                int row = xidx[b * 512 + lg];
                v = *(const short8*)&embT[row * 112 + c8 * 8];
            }
            *(short8*)&s_e[j * SSTR + c8 * 8] = v;
        }
    }

    // per-lane B byte offsets for all 10 k-steps (row n+dk, col c0)
    int bofs[10], bofs4[10];
#pragma unroll
    for (int ks = 0; ks < 10; ++ks) {
        int oct = ks * 4 + q;
        int dk = (oct >= 39) ? 3 : (oct >= 26) ? 2 : (oct >= 13) ? 1 : 0;
        int c0 = (oct - 13 * dk) * 8;
        bofs[ks] = ((n + dk) * SSTR + c0) * 2;
        int r4 = 64 + n + dk; if (r4 > 69) r4 = 69;  // discarded rows only
        bofs4[ks] = (r4 * SSTR + c0) * 2;
    }
    float* hps = hpart + ((b * 8 + bx) * 2 + (wv & 1)) * 112;
    short* gouts = locT + ((size_t)b * 512 + l0) * 112;

    __syncthreads();
    const bool edge = (bx == 0) || (bx == 7);

#define PASS3T(Ap, SRC, DST, BIAS, R0L, PL, E)                                   \
    if (wv == 0)      ctap<4,3,0,0,false,PL,false,E>(Ap,SRC,DST,nullptr,bofs,bofs4,BIAS,R0L,l0,hps,lane); \
    else if (wv == 1) ctap<4,2,0,3,true, PL,false,E>(Ap,SRC,DST,nullptr,bofs,bofs4,BIAS,R0L,l0,hps,lane); \
    else if (wv == 2) ctap<3,3,4,0,false,PL,false,E>(Ap,SRC,DST,nullptr,bofs,bofs4,BIAS,R0L,l0,hps,lane); \
    else              ctap<3,2,4,3,true, PL,false,E>(Ap,SRC,DST,nullptr,bofs,bofs4,BIAS,R0L,l0,hps,lane);

    if (edge) {
        PASS3T(A1, s_e, s_h, b1, l0 - 2, true, true)
        __syncthreads();
        PASS3T(A2, s_h, s_e, b2, l0 - 1, false, true)
    } else {
        PASS3T(A1, s_e, s_h, b1, l0 - 2, true, false)
        __syncthreads();
        PASS3T(A2, s_h, s_e, b2, l0 - 1, false, false)
    }
    __syncthreads();
    // li: outputs l in [l0, l0+63] always valid
    if (wv == 0)      ctap<4,2,0,0,false,false,true,false>(A3,s_e,nullptr,gouts,bofs,bofs4,b3,l0,l0,hps,lane);
    else if (wv == 1) ctap<4,2,0,2,false,false,true,false>(A3,s_e,nullptr,gouts,bofs,bofs4,b3,l0,l0,hps,lane);
    else if (wv == 2) ctap<3,2,4,0,false,false,true,false>(A3,s_e,nullptr,gouts,bofs,bofs4,b3,l0,l0,hps,lane);
    else              ctap<3,2,4,2,false,false,true,false>(A3,s_e,nullptr,gouts,bofs,bofs4,b3,l0,l0,hps,lane);
#undef PASS3T
}

// ---------------------------------------------------------------------------
// conv3 (1x1, loc half) + conv4 -> logits, with the gate/zg computation
// folded in as a per-block LDS prologue (kills the pool_gate launch + zg
// global round-trip; ~33K redundant FMA/block = ~0.5 us aggregate).
// Column-band c3tile: each wave owns ALL 7 f-rows x 2 nt cols -> complete
// logits for its 32 columns, no cross-wave partial add. SSTR=136 (aligned).
// LDS 128*SSTR*2 + 452*4 = 36624 B -> 4 blocks/CU.
// ---------------------------------------------------------------------------
template<int NTB>
DEV void c3tile(const short* s_in, float* s_part, const short* __restrict__ A4,
                const float* s_zg, const float* __restrict__ w4, int lane) {
    const int q = lane >> 4, n = lane & 15;
    const f32x4 z4 = {0.f, 0.f, 0.f, 0.f};
    f32x4 acc[7][2];
#pragma unroll
    for (int mt = 0; mt < 7; ++mt) {
        int fb = mt * 16 + q * 4;
        f32x4 zgv = *(const f32x4*)&s_zg[fb];   // pad entries are 0
#pragma unroll
        for (int nt = 0; nt < 2; ++nt) acc[mt][nt] = zgv;
    }
#pragma unroll
    for (int ks = 0; ks < 4; ++ks) {
        short8 a[7];
#pragma unroll
        for (int mt = 0; mt < 7; ++mt)
            a[mt] = *(const short8*)&A4[(ks * 448 + mt * 64 + lane) * 8];
        int c0 = (ks * 4 + q) * 8;
        if (c0 > 104) c0 = 104;   // A zero for kappa>=100; cols 104.. are 0
        const char* bp = (const char*)(s_in + n * SSTR + c0);
        short8 bf[2];
#pragma unroll
        for (int nt = 0; nt < 2; ++nt)
            bf[nt] = *(const short8*)(bp + (NTB + nt) * ROWB);
#pragma unroll
        for (int mt = 0; mt < 7; ++mt)
#pragma unroll
            for (int nt = 0; nt < 2; ++nt)
                acc[mt][nt] = __builtin_amdgcn_mfma_f32_16x16x32_bf16(
                    a[mt], bf[nt], acc[mt][nt], 0, 0, 0);
    }
#pragma unroll
    for (int nt = 0; nt < 2; ++nt) {
        float part = 0.f;
#pragma unroll
        for (int mt = 0; mt < 7; ++mt) {
            const int fb = mt * 16 + q * 4;
            f32x4 w4v = (fb < 100) ? *(const f32x4*)&w4[fb] : z4;
#pragma unroll
            for (int r = 0; r < 4; ++r)
                part += fmaxf(acc[mt][nt][r], 0.f) * w4v[r];
        }
        part += __shfl_xor(part, 16, 64);
        part += __shfl_xor(part, 32, 64);
        if (q == 0) s_part[(NTB + nt) * 16 + n] = part;   // full logit
    }
}

__global__ __launch_bounds__(256, 4) void conv3_logits_kernel(
    const short* __restrict__ locT, const short* __restrict__ A4,
    const float* __restrict__ hpart, const float* __restrict__ gi_w,
    const float* __restrict__ gi_b, const float* __restrict__ w3,
    const float* __restrict__ b3, const float* __restrict__ w4,
    const float* __restrict__ b4, float* __restrict__ logits) {
    extern __shared__ char smem[];
    short* s_in = (short*)smem;                       // [128][SSTR]
    float* s_part = (float*)(smem + 128 * SSTR * 2);  // [128]
    float* s_zg = s_part + 128;                       // [112]
    float* s_hm = s_zg + 112;                         // [112]
    float* s_g = s_hm + 112;                          // [100]
    const int tid = threadIdx.x;
    const int b = blockIdx.y, l0r = blockIdx.x * 128;
    const int lane = tid & 63, wv = tid >> 6;

    // issue staging loads first (latency hides under the zg prologue)
    short8 tmp[8];
#pragma unroll
    for (int p = 0; p < 8; ++p) {
        int idx = tid + p * 256;
        int j = idx >> 4, c8 = idx & 15;
        if (c8 < 14)
            tmp[p] = *(const short8*)&locT[((size_t)b * 512 + l0r + j) * 112 + c8 * 8];
    }

    // zg prologue: hm = pooled h mean; g = relu(gi MLP); zg = b3 + w3.g
    if (tid < 112) {
        float a = 0.f;
#pragma unroll
        for (int s = 0; s < 16; ++s) a += hpart[(b * 16 + s) * 112 + tid];
        s_hm[tid] = a * (1.f / 512.f);
    }
    __syncthreads();
    if (tid < 100) {
        float a = gi_b[tid];
        for (int f = 0; f < 100; ++f) a += s_hm[f] * gi_w[tid * 100 + f];
        s_g[tid] = fmaxf(a, 0.f);
    }
    __syncthreads();
    if (tid < 112) {
        float a = 0.f;
        if (tid < 100) {
            a = b3[tid];
            for (int h = 0; h < 100; ++h) a += s_g[h] * w3[tid * 200 + h];
        }
        s_zg[tid] = a;
    }

#pragma unroll
    for (int p = 0; p < 8; ++p) {
        int idx = tid + p * 256;
        int j = idx >> 4, c8 = idx & 15;
        if (c8 < 14)
            *(short8*)&s_in[j * SSTR + c8 * 8] = tmp[p];
    }
    __syncthreads();
    if (wv == 0)      c3tile<0>(s_in, s_part, A4, s_zg, w4, lane);
    else if (wv == 1) c3tile<2>(s_in, s_part, A4, s_zg, w4, lane);
    else if (wv == 2) c3tile<4>(s_in, s_part, A4, s_zg, w4, lane);
    else              c3tile<6>(s_in, s_part, A4, s_zg, w4, lane);
    __syncthreads();
    if (tid < 128)
        logits[b * 512 + l0r + tid] = s_part[tid] + b4[0];
}

// ---------------------------------------------------------------------------
// Fused sampler + distil head, one block per b (byte-exact r0). Wave-
// parallel over k: wave wv handles k = wv, wv+4, wv+8 (<10) with wave-local
// shuffle softmax. Merge via LDS max, then pooled gather (bf16 embT),
// fc1 relu, sigmoid head.
// ---------------------------------------------------------------------------
__global__ __launch_bounds__(256) void samp_head_kernel(
    const float* __restrict__ u, const float* __restrict__ logits,
    const int* __restrict__ xidx, const short* __restrict__ embT,
    const float* __restrict__ f1w, const float* __restrict__ f1b,
    const float* __restrict__ hw, const float* __restrict__ hb,
    float* __restrict__ cs_out, float* __restrict__ out) {
    const float EPSV = 1.1920929e-07f;
    const float INVT = 1.f / 0.3f;
    int b = blockIdx.x, tid = threadIdx.x;
    int lane = tid & 63, wv = tid >> 6;
    __shared__ float s_logT[512], s_cs[512];
    __shared__ int s_x[512];
    __shared__ float s_csw[4][512];
    __shared__ float s_acc[16][112];
    __shared__ float s_pool[112], s_h2[100], s_fin[4];
    for (int l = tid; l < 512; l += 256) {
        s_logT[l] = logits[b * 512 + l] * INVT;
        s_x[l] = xidx[b * 512 + l];
    }
    __syncthreads();
    // wave-local softmax per k
    const int nk = (wv < 2) ? 3 : 2;
    float csl[8];
#pragma unroll
    for (int i = 0; i < 8; ++i) csl[i] = 0.f;
    float lt[8];
#pragma unroll
    for (int i = 0; i < 8; ++i) lt[i] = s_logT[lane * 8 + i];
    for (int j = 0; j < nk; ++j) {
        int k = wv + 4 * j;
        f32x4 u0 = *(const f32x4*)&u[(b * 10 + k) * 512 + lane * 8];
        f32x4 u1 = *(const f32x4*)&u[(b * 10 + k) * 512 + lane * 8 + 4];
        float nz[8];
#pragma unroll
        for (int i = 0; i < 8; ++i) {
            float vv = (i < 4) ? u0[i] : u1[i - 4];
            vv = fminf(fmaxf(vv, EPSV), 1.f - EPSV);
            nz[i] = -__logf(-__logf(vv)) * INVT + lt[i];
        }
        float m = nz[0];
#pragma unroll
        for (int i = 1; i < 8; ++i) m = fmaxf(m, nz[i]);
#pragma unroll
        for (int off = 1; off <= 32; off <<= 1) m = fmaxf(m, __shfl_xor(m, off, 64));
        float e[8], s = 0.f;
#pragma unroll
        for (int i = 0; i < 8; ++i) { e[i] = __expf(nz[i] - m); s += e[i]; }
#pragma unroll
        for (int off = 1; off <= 32; off <<= 1) s += __shfl_xor(s, off, 64);
        float inv = 1.f / s;
#pragma unroll
        for (int i = 0; i < 8; ++i) csl[i] = fmaxf(csl[i], e[i] * inv);
    }
#pragma unroll
    for (int i = 0; i < 8; ++i) s_csw[wv][lane * 8 + i] = csl[i];
    __syncthreads();
    for (int l = tid; l < 512; l += 256) {
        float c = fmaxf(fmaxf(s_csw[0][l], s_csw[1][l]),
                        fmaxf(s_csw[2][l], s_csw[3][l]));
        s_cs[l] = c;
        cs_out[b * 512 + l] = c;
    }
    __syncthreads();
    // pooled partial sums: thread (jg, c8) covers l = jg+16t, channels c8*8..+7
    int jg = tid >> 4, c8 = tid & 15;
    if (c8 < 14) {
        f32x4 pa = {0.f, 0.f, 0.f, 0.f}, pb = {0.f, 0.f, 0.f, 0.f};
#pragma unroll 4
        for (int l = jg; l < 512; l += 16) {
            int row = s_x[l];
            float cv = s_cs[l];
            short8 e8 = *(const short8*)&embT[(size_t)row * 112 + c8 * 8];
#pragma unroll
            for (int r = 0; r < 4; ++r) {
                pa[r] += cv * bfu(e8[r]);
                pb[r] += cv * bfu(e8[4 + r]);
            }
        }
        *(f32x4*)&s_acc[jg][c8 * 8] = pa;
        *(f32x4*)&s_acc[jg][c8 * 8 + 4] = pb;
    }
    __syncthreads();
    if (tid < 112) {
        float p = 0.f;
#pragma unroll
        for (int g = 0; g < 16; ++g) p += s_acc[g][tid];
        s_pool[tid] = p * (1.f / 512.f);
    }
    __syncthreads();
    if (tid < 100) {
        float a = f1b[tid];
        for (int i = 0; i < 100; ++i) a += s_pool[i] * f1w[tid * 100 + i];
        s_h2[tid] = fmaxf(a, 0.f);
    }
    __syncthreads();
    float v = (tid < 100) ? s_h2[tid] * hw[tid] : 0.f;
#pragma unroll
    for (int off = 32; off >= 1; off >>= 1) v += __shfl_xor(v, off, 64);
    if (lane == 0) s_fin[wv] = v;
    __syncthreads();
    if (tid == 0) {
        float z = s_fin[0] + s_fin[1] + s_fin[2] + s_fin[3] + hb[0];
        out[b] = 1.f / (1.f + __expf(-z));
    }
}

// ---------------------------------------------------------------------------
extern "C" void kernel_launch(void* const* d_in, const int* in_sizes, int n_in,
                              void* d_out, int out_size, void* d_ws, size_t ws_size,
                              hipStream_t stream) {
    const int*   x   = (const int*)d_in[0];
    const float* u   = (const float*)d_in[1];
    const float* emb = (const float*)d_in[2];
    const float* c1w = (const float*)d_in[3];
    const float* c1b = (const float*)d_in[4];
    const float* giw = (const float*)d_in[5];
    const float* gib = (const float*)d_in[6];
    const float* c2w = (const float*)d_in[7];
    const float* c2b = (const float*)d_in[8];
    const float* liw = (const float*)d_in[9];
    const float* lib = (const float*)d_in[10];
    const float* c3w = (const float*)d_in[11];
    const float* c3b = (const float*)d_in[12];
    const float* c4w = (const float*)d_in[13];
    const float* c4b = (const float*)d_in[14];
    const float* f1w = (const float*)d_in[15];
    const float* f1b = (const float*)d_in[16];
    const float* hww = (const float*)d_in[17];
    const float* hbb = (const float*)d_in[18];
    float* out = (float*)d_out;

    char* ws = (char*)d_ws;
    short* locT   = (short*)(ws + 0);           // [512][512][112] bf16 (58.7 MB)
    short* embT   = (short*)(ws + 58720256);    // [100000][112] bf16 (22.4 MB)
    short* A1     = (short*)(ws + 81120256);    // 10*448*16 B each
    short* A2     = (short*)(ws + 81191936);
    short* A3     = (short*)(ws + 81263616);
    short* A4     = (short*)(ws + 81335296);    // 4*448*16 B
    float* logits = (float*)(ws + 81593344);    // [512][512]
    float* hpart  = (float*)(ws + 82641920);    // [512][8][2][112]

    prep_kernel<<<12738, 256, 0, stream>>>(emb, embT, c1w, c2w, liw, c3w,
                                           A1, A2, A3, A4);

    size_t smemA = (size_t)2 * 72 * SSTR * 2;            // 39168 B
    fused_conv_kernel<<<dim3(8, 512), 256, smemA, stream>>>(
        x, embT, A1, A2, A3, c1b, c2b, lib, locT, hpart);
    size_t smemB = (size_t)128 * SSTR * 2 + 452 * 4;     // 36624 B
    conv3_logits_kernel<<<dim3(4, 512), 256, smemB, stream>>>(
        locT, A4, hpart, giw, gib, c3w, c3b, c4w, c4b, logits);
    samp_head_kernel<<<512, 256, 0, stream>>>(
        u, logits, x, embT, f1w, f1b, hww, hbb, out + 512, out);
}

// Round 7
// 262.030 us; speedup vs baseline: 3.8833x; 1.0057x over previous
//
#include <hip/hip_runtime.h>
#include <math.h>

#define DEV __device__ __forceinline__

typedef __attribute__((ext_vector_type(8))) short short8;
typedef __attribute__((ext_vector_type(4))) short short4v;
typedef __attribute__((ext_vector_type(4))) float f32x4;
typedef __attribute__((ext_vector_type(2))) unsigned uint2v;

// LDS row stride in shorts (272 B = 68 words; 68 mod 32 = 4 -> b128 reads
// land 2-way on banks = free per m136). MUST be a multiple of 8 shorts:
// SSTR=114 (r4/r5) gave 4-mod-16 ds_*_b128 addresses -- correct results but
// ~60% LDS-throughput penalty (116 -> 187 us) with conflicts reading 0.
#define SSTR 136
#define ROWB (16 * SSTR * 2)   // 4352 B per 16-row tile

DEV short f2bf(float f) {
    unsigned u = __builtin_bit_cast(unsigned, f);
    unsigned r = (u + 0x7fffu + ((u >> 16) & 1u)) >> 16;
    return (short)r;
}

#if __has_builtin(__builtin_amdgcn_cvt_pk_bf16_f32)
DEV unsigned pk2bf(float a, float b) {
    auto v = __builtin_amdgcn_cvt_pk_bf16_f32(a, b);
    return __builtin_bit_cast(unsigned, v);
}
#else
DEV unsigned pk2bf(float a, float b) {
    return ((unsigned)(unsigned short)f2bf(a)) |
           (((unsigned)(unsigned short)f2bf(b)) << 16);
}
#endif

DEV float bfu(short s) {
    unsigned u = ((unsigned)(unsigned short)s) << 16;
    return __builtin_bit_cast(float, u);
}

// ---------------------------------------------------------------------------
// prep: blocks 0..12499 = emb cvt (f32 [V][100] -> bf16 [V][112], pad cols
// zeroed, 8 rows/block); blocks 12500..12737 = weight packing into MFMA
// A-frag order; blocks 12738/12739 = gate-weight transposes (giwT[f][t] =
// gi_w[t][f], w3T[h][f] = c3w[f][h]) so the zg prologue reads coalesced.
// ---------------------------------------------------------------------------
__global__ __launch_bounds__(256) void prep_kernel(
    const float* __restrict__ emb, short* __restrict__ embT,
    const float* __restrict__ c1w, const float* __restrict__ c2w,
    const float* __restrict__ liw, const float* __restrict__ c3w,
    const float* __restrict__ giw,
    short* __restrict__ A1, short* __restrict__ A2,
    short* __restrict__ A3, short* __restrict__ A4,
    float* __restrict__ giwT, float* __restrict__ w3T) {
    int bxg = blockIdx.x;
    if (bxg < 12500) {
        int t = threadIdx.x;
        int row = bxg * 8 + (t >> 5);
        int c4 = t & 31;
        if (c4 >= 28) return;
        short4v v = {0, 0, 0, 0};
        if (c4 < 25) {
            f32x4 e = *(const f32x4*)&emb[row * 100 + c4 * 4];
#pragma unroll
            for (int r = 0; r < 4; ++r) v[r] = f2bf(e[r]);
        }
        *(short4v*)&embT[row * 112 + c4 * 4] = v;
        return;
    }
    if (bxg >= 12738) {
        // transposes: 100x100 each, one block apiece
        int t = threadIdx.x;
        if (bxg == 12738) {
            for (int i = t; i < 10000; i += 256) {
                int f = i / 100, g = i % 100;           // giwT[f][g]
                giwT[f * 100 + g] = giw[g * 100 + f];
            }
        } else {
            for (int i = t; i < 10000; i += 256) {
                int h = i / 100, f = i % 100;           // w3T[h][f]
                w3T[h * 100 + f] = c3w[f * 200 + h];
            }
        }
        return;
    }
    if (threadIdx.x >= 64) return;
    int bx = bxg - 12500;
    const float* w; short* dst; int mode, lbx;
    if (bx < 70)       { w = c1w; dst = A1; mode = 0; lbx = bx; }
    else if (bx < 140) { w = c2w; dst = A2; mode = 0; lbx = bx - 70; }
    else if (bx < 210) { w = liw; dst = A3; mode = 0; lbx = bx - 140; }
    else               { w = c3w; dst = A4; mode = 1; lbx = bx - 210; }
    int lane = threadIdx.x;
    int f = lbx % 7 * 16 + (lane & 15);
    int kb = (lbx / 7) * 32 + (lane >> 4) * 8;
    short8 v;
#pragma unroll
    for (int j = 0; j < 8; ++j) {
        int kk = kb + j;
        float val = 0.f;
        if (f < 100) {
            if (mode == 0) {
                int oct = kk >> 3, dk = oct / 13;
                int c = (oct - 13 * dk) * 8 + (kk & 7);
                if (dk < 3 && c < 100) val = w[(f * 100 + c) * 3 + dk];
            } else {
                if (kk < 100) val = w[f * 200 + 100 + kk];
            }
        }
        v[j] = f2bf(val);
    }
    *(short8*)&dst[(lbx * 64 + lane) * 8] = v;
}

// ---------------------------------------------------------------------------
// One 3-tap conv pass, BALANCED tile (r0-proven): this wave owns mt
// [MTB,MTB+MT) x nt [NTB,NTB+NT). B-reads amortize over MT MFMAs, A-rows
// over NT. Accumulator init = bias. CLAMPL: the nt==4 tile reads clamped
// rows (feeds only discarded outputs; halo chain loc<=63 -> c2<=65 ->
// h<=67 -> e<=69 all real). EDGE: l-range zeroing only in bx 0/7.
// POOL: relu partial sums for l in [l0,l0+64) -> hpart_slot[112].
// ---------------------------------------------------------------------------
template<int MT, int NT, int MTB, int NTB, bool CLAMPL, bool POOL,
         bool TO_GLOBAL, bool EDGE>
DEV void ctap(const short* __restrict__ Ap, const short* s_src, short* s_dst,
              short* __restrict__ gout, const int* bofs, const int* bofs4,
              const float* __restrict__ bias, int row0l, int l0,
              float* __restrict__ hpart_slot, int lane) {
    const int q = lane >> 4, n = lane & 15;
    const f32x4 z4 = {0.f, 0.f, 0.f, 0.f};
    f32x4 acc[MT][NT];
#pragma unroll
    for (int mt = 0; mt < MT; ++mt) {
        int fb = (MTB + mt) * 16 + q * 4;
        f32x4 bs = (fb < 100) ? *(const f32x4*)&bias[fb] : z4;
#pragma unroll
        for (int nt = 0; nt < NT; ++nt) acc[mt][nt] = bs;
    }
#pragma unroll
    for (int ks = 0; ks < 10; ++ks) {
        short8 a[MT];
#pragma unroll
        for (int mt = 0; mt < MT; ++mt)
            a[mt] = *(const short8*)&Ap[(ks * 448 + (MTB + mt) * 64 + lane) * 8];
        const char* bp = (const char*)s_src + bofs[ks];
        short8 bf[NT];
#pragma unroll
        for (int nt = 0; nt < NT; ++nt) {
            if (CLAMPL && (NTB + nt) == 4)
                bf[nt] = *(const short8*)((const char*)s_src + bofs4[ks]);
            else
                bf[nt] = *(const short8*)(bp + (NTB + nt) * ROWB);
        }
#pragma unroll
        for (int mt = 0; mt < MT; ++mt)
#pragma unroll
            for (int nt = 0; nt < NT; ++nt)
                acc[mt][nt] = __builtin_amdgcn_mfma_f32_16x16x32_bf16(
                    a[mt], bf[nt], acc[mt][nt], 0, 0, 0);
    }
    f32x4 ps[MT];
    if constexpr (POOL) {
#pragma unroll
        for (int mt = 0; mt < MT; ++mt) ps[mt] = z4;
    }
#pragma unroll
    for (int nt = 0; nt < NT; ++nt) {
        const int j = (NTB + nt) * 16 + n;
        const int l = row0l + j;
        bool lok = true;
        if constexpr (EDGE) lok = ((unsigned)l < 512u);
        const bool pok = POOL && (l >= l0) && (l < l0 + 64);
#pragma unroll
        for (int mt = 0; mt < MT; ++mt) {
            const int fb = (MTB + mt) * 16 + q * 4;
            f32x4 v;
#pragma unroll
            for (int r = 0; r < 4; ++r) {
                v[r] = fmaxf(acc[mt][nt][r], 0.f);
                if constexpr (EDGE) v[r] = lok ? v[r] : 0.f;
            }
            if constexpr (POOL) {
                if (pok) {
#pragma unroll
                    for (int r = 0; r < 4; ++r) ps[mt][r] += v[r];
                }
            }
            uint2v pk;
            pk[0] = pk2bf(v[0], v[1]); pk[1] = pk2bf(v[2], v[3]);
            if constexpr (TO_GLOBAL) {
                *(uint2v*)&gout[j * 112 + fb] = pk;
            } else {
                if ((NTB + nt) < 4 || n < 6)      // store rows j < 70 only
                    *(uint2v*)&s_dst[j * SSTR + fb] = pk;
            }
        }
    }
    if constexpr (POOL) {
#pragma unroll
        for (int mt = 0; mt < MT; ++mt)
#pragma unroll
            for (int off = 1; off <= 8; off <<= 1)
#pragma unroll
                for (int r = 0; r < 4; ++r)
                    ps[mt][r] += __shfl_xor(ps[mt][r], off, 64);
        if (n == 0) {
#pragma unroll
            for (int mt = 0; mt < MT; ++mt)
                *(f32x4*)&hpart_slot[(MTB + mt) * 16 + q * 4] = ps[mt];
        }
    }
}

// ---------------------------------------------------------------------------
// Fused conv1 -> conv2 -> li, 64-wide l-tile, 256 threads (4 waves), grid
// (8,512) -- the proven structure (frozen; measured 100.6 us r6). Staging =
// VGPR gather + ds_write (global_load_lds with scattered sources serializes
// the LDS-DMA: 3.6x regression, r2). Balanced wave tiles: wv0=(4,3)@(0,0)
// wv1=(4,2)@(0,3) wv2=(3,3)@(4,0) wv3=(3,2)@(4,3); li: NT=2 each @(0/4,0/2).
// Reg budget ~64 VGPR + 64 AGPR = 128/wave -> 4 waves/SIMD is the ceiling
// (min-waves=5 spilled ~100 B/thread, r4). LDS 2*72*SSTR*2 = 39168 B.
// ---------------------------------------------------------------------------
__global__ __launch_bounds__(256, 4) void fused_conv_kernel(
    const int* __restrict__ xidx, const short* __restrict__ embT,
    const short* __restrict__ A1, const short* __restrict__ A2,
    const short* __restrict__ A3,
    const float* __restrict__ b1, const float* __restrict__ b2,
    const float* __restrict__ b3,
    short* __restrict__ locT, float* __restrict__ hpart) {
    extern __shared__ char smem[];
    short* s_e = (short*)smem;                    // [72][SSTR], later c2
    short* s_h = (short*)(smem + 72 * SSTR * 2);  // [72][SSTR]
    const int tid = threadIdx.x;
    const int b = blockIdx.y, bx = blockIdx.x, l0 = bx * 64;
    const int lane = tid & 63, wv = tid >> 6;
    const int q = lane >> 4, n = lane & 15;

    // stage e: 70 rows x 14 b128 chunks (virtual 16-grid; c8>=14 skipped)
#pragma unroll
    for (int p = 0; p < 5; ++p) {
        int idx = tid + p * 256;           // 0..1279, need j<70
        int j = idx >> 4, c8 = idx & 15;
        if (j < 70 && c8 < 14) {
            int lg = l0 - 3 + j;
            short8 v = {0, 0, 0, 0, 0, 0, 0, 0};
            if (lg >= 0 && lg < 512) {
                int row = xidx[b * 512 + lg];
                v = *(const short8*)&embT[row * 112 + c8 * 8];
            }
            *(short8*)&s_e[j * SSTR + c8 * 8] = v;
        }
    }

    // per-lane B byte offsets for all 10 k-steps (row n+dk, col c0)
    int bofs[10], bofs4[10];
#pragma unroll
    for (int ks = 0; ks < 10; ++ks) {
        int oct = ks * 4 + q;
        int dk = (oct >= 39) ? 3 : (oct >= 26) ? 2 : (oct >= 13) ? 1 : 0;
        int c0 = (oct - 13 * dk) * 8;
        bofs[ks] = ((n + dk) * SSTR + c0) * 2;
        int r4 = 64 + n + dk; if (r4 > 69) r4 = 69;  // discarded rows only
        bofs4[ks] = (r4 * SSTR + c0) * 2;
    }
    float* hps = hpart + ((b * 8 + bx) * 2 + (wv & 1)) * 112;
    short* gouts = locT + ((size_t)b * 512 + l0) * 112;

    __syncthreads();
    const bool edge = (bx == 0) || (bx == 7);

#define PASS3T(Ap, SRC, DST, BIAS, R0L, PL, E)                                   \
    if (wv == 0)      ctap<4,3,0,0,false,PL,false,E>(Ap,SRC,DST,nullptr,bofs,bofs4,BIAS,R0L,l0,hps,lane); \
    else if (wv == 1) ctap<4,2,0,3,true, PL,false,E>(Ap,SRC,DST,nullptr,bofs,bofs4,BIAS,R0L,l0,hps,lane); \
    else if (wv == 2) ctap<3,3,4,0,false,PL,false,E>(Ap,SRC,DST,nullptr,bofs,bofs4,BIAS,R0L,l0,hps,lane); \
    else              ctap<3,2,4,3,true, PL,false,E>(Ap,SRC,DST,nullptr,bofs,bofs4,BIAS,R0L,l0,hps,lane);

    if (edge) {
        PASS3T(A1, s_e, s_h, b1, l0 - 2, true, true)
        __syncthreads();
        PASS3T(A2, s_h, s_e, b2, l0 - 1, false, true)
    } else {
        PASS3T(A1, s_e, s_h, b1, l0 - 2, true, false)
        __syncthreads();
        PASS3T(A2, s_h, s_e, b2, l0 - 1, false, false)
    }
    __syncthreads();
    // li: outputs l in [l0, l0+63] always valid
    if (wv == 0)      ctap<4,2,0,0,false,false,true,false>(A3,s_e,nullptr,gouts,bofs,bofs4,b3,l0,l0,hps,lane);
    else if (wv == 1) ctap<4,2,0,2,false,false,true,false>(A3,s_e,nullptr,gouts,bofs,bofs4,b3,l0,l0,hps,lane);
    else if (wv == 2) ctap<3,2,4,0,false,false,true,false>(A3,s_e,nullptr,gouts,bofs,bofs4,b3,l0,l0,hps,lane);
    else              ctap<3,2,4,2,false,false,true,false>(A3,s_e,nullptr,gouts,bofs,bofs4,b3,l0,l0,hps,lane);
#undef PASS3T
}

// ---------------------------------------------------------------------------
// conv3 (1x1, loc half) + conv4 -> logits, zg prologue folded in. NO LDS
// STAGING: ownership analysis shows each locT element is read by exactly one
// lane of one wave (column-band waves own disjoint rows; (ks,q) octets cover
// disjoint cols) -- zero reuse, so B-fragments are read STRAIGHT FROM GLOBAL
// (each wave load = 16 rows x 64 contiguous bytes = full cache lines).
// Removes 28.7 KB of staging regs, the LDS round-trip, and a barrier.
// zg prologue now reads transposed giwT/w3T -> coalesced.
// ---------------------------------------------------------------------------
template<int NTB>
DEV void c3tile(const short* __restrict__ locB, float* s_part,
                const short* __restrict__ A4, const float* s_zg,
                const float* __restrict__ w4, int lane) {
    const int q = lane >> 4, n = lane & 15;
    const f32x4 z4 = {0.f, 0.f, 0.f, 0.f};
    f32x4 acc[7][2];
#pragma unroll
    for (int mt = 0; mt < 7; ++mt) {
        int fb = mt * 16 + q * 4;
        f32x4 zgv = *(const f32x4*)&s_zg[fb];   // pad entries are 0
#pragma unroll
        for (int nt = 0; nt < 2; ++nt) acc[mt][nt] = zgv;
    }
#pragma unroll
    for (int ks = 0; ks < 4; ++ks) {
        short8 a[7];
#pragma unroll
        for (int mt = 0; mt < 7; ++mt)
            a[mt] = *(const short8*)&A4[(ks * 448 + mt * 64 + lane) * 8];
        int c0 = (ks * 4 + q) * 8;
        if (c0 > 104) c0 = 104;   // A zero for kappa>=100; cols 104.. are 0
        const short* bp = locB + n * 112 + c0;
        short8 bf[2];
#pragma unroll
        for (int nt = 0; nt < 2; ++nt)
            bf[nt] = *(const short8*)(bp + (NTB + nt) * 16 * 112);
#pragma unroll
        for (int mt = 0; mt < 7; ++mt)
#pragma unroll
            for (int nt = 0; nt < 2; ++nt)
                acc[mt][nt] = __builtin_amdgcn_mfma_f32_16x16x32_bf16(
                    a[mt], bf[nt], acc[mt][nt], 0, 0, 0);
    }
#pragma unroll
    for (int nt = 0; nt < 2; ++nt) {
        float part = 0.f;
#pragma unroll
        for (int mt = 0; mt < 7; ++mt) {
            const int fb = mt * 16 + q * 4;
            f32x4 w4v = (fb < 100) ? *(const f32x4*)&w4[fb] : z4;
#pragma unroll
            for (int r = 0; r < 4; ++r)
                part += fmaxf(acc[mt][nt][r], 0.f) * w4v[r];
        }
        part += __shfl_xor(part, 16, 64);
        part += __shfl_xor(part, 32, 64);
        if (q == 0) s_part[(NTB + nt) * 16 + n] = part;   // full logit
    }
}

__global__ __launch_bounds__(256, 4) void conv3_logits_kernel(
    const short* __restrict__ locT, const short* __restrict__ A4,
    const float* __restrict__ hpart, const float* __restrict__ giwT,
    const float* __restrict__ gi_b, const float* __restrict__ w3T,
    const float* __restrict__ b3, const float* __restrict__ w4,
    const float* __restrict__ b4, float* __restrict__ logits) {
    __shared__ float s_part[128];
    __shared__ float s_zg[112];
    __shared__ float s_hm[112];
    __shared__ float s_g[100];
    const int tid = threadIdx.x;
    const int b = blockIdx.y, l0r = blockIdx.x * 128;
    const int lane = tid & 63, wv = tid >> 6;

    // zg prologue: hm = pooled h mean; g = relu(gi MLP); zg = b3 + w3.g
    if (tid < 112) {
        float a = 0.f;
#pragma unroll
        for (int s = 0; s < 16; ++s) a += hpart[(b * 16 + s) * 112 + tid];
        s_hm[tid] = a * (1.f / 512.f);
    }
    __syncthreads();
    if (tid < 100) {
        float a = gi_b[tid];
        for (int f = 0; f < 100; ++f) a += s_hm[f] * giwT[f * 100 + tid];
        s_g[tid] = fmaxf(a, 0.f);
    }
    __syncthreads();
    if (tid < 112) {
        float a = 0.f;
        if (tid < 100) {
            a = b3[tid];
            for (int h = 0; h < 100; ++h) a += s_g[h] * w3T[h * 100 + tid];
        }
        s_zg[tid] = a;
    }
    __syncthreads();

    const short* locB = locT + ((size_t)b * 512 + l0r) * 112;
    if (wv == 0)      c3tile<0>(locB, s_part, A4, s_zg, w4, lane);
    else if (wv == 1) c3tile<2>(locB, s_part, A4, s_zg, w4, lane);
    else if (wv == 2) c3tile<4>(locB, s_part, A4, s_zg, w4, lane);
    else              c3tile<6>(locB, s_part, A4, s_zg, w4, lane);
    __syncthreads();
    if (tid < 128)
        logits[b * 512 + l0r + tid] = s_part[tid] + b4[0];
}

// ---------------------------------------------------------------------------
// Fused sampler + distil head, one block per b, 512 THREADS (8 waves; was 4
// -- doubles resident waves/CU on this latency-bound kernel). Wave wv
// handles k = wv, wv+8 (<10) with wave-local shuffle softmax. Merge via LDS
// max, then pooled gather (bf16 embT, 16 l-iters/thread), fc1 relu, head.
// ---------------------------------------------------------------------------
__global__ __launch_bounds__(512) void samp_head_kernel(
    const float* __restrict__ u, const float* __restrict__ logits,
    const int* __restrict__ xidx, const short* __restrict__ embT,
    const float* __restrict__ f1w, const float* __restrict__ f1b,
    const float* __restrict__ hw, const float* __restrict__ hb,
    float* __restrict__ cs_out, float* __restrict__ out) {
    const float EPSV = 1.1920929e-07f;
    const float INVT = 1.f / 0.3f;
    int b = blockIdx.x, tid = threadIdx.x;
    int lane = tid & 63, wv = tid >> 6;   // 8 waves
    __shared__ float s_logT[512], s_cs[512];
    __shared__ int s_x[512];
    __shared__ float s_csw[8][512];
    __shared__ float s_acc[32][112];
    __shared__ float s_pool[112], s_h2[100], s_fin[8];
    if (tid < 512) {
        s_logT[tid] = logits[b * 512 + tid] * INVT;
        s_x[tid] = xidx[b * 512 + tid];
    }
    __syncthreads();
    // wave-local softmax per k: waves 0,1 take 2 k's, waves 2-7 take 1
    const int nk = (wv < 2) ? 2 : 1;
    float csl[8];
#pragma unroll
    for (int i = 0; i < 8; ++i) csl[i] = 0.f;
    float lt[8];
#pragma unroll
    for (int i = 0; i < 8; ++i) lt[i] = s_logT[lane * 8 + i];
    for (int j = 0; j < nk; ++j) {
        int k = wv + 8 * j;
        f32x4 u0 = *(const f32x4*)&u[(b * 10 + k) * 512 + lane * 8];
        f32x4 u1 = *(const f32x4*)&u[(b * 10 + k) * 512 + lane * 8 + 4];
        float nz[8];
#pragma unroll
        for (int i = 0; i < 8; ++i) {
            float vv = (i < 4) ? u0[i] : u1[i - 4];
            vv = fminf(fmaxf(vv, EPSV), 1.f - EPSV);
            nz[i] = -__logf(-__logf(vv)) * INVT + lt[i];
        }
        float m = nz[0];
#pragma unroll
        for (int i = 1; i < 8; ++i) m = fmaxf(m, nz[i]);
#pragma unroll
        for (int off = 1; off <= 32; off <<= 1) m = fmaxf(m, __shfl_xor(m, off, 64));
        float e[8], s = 0.f;
#pragma unroll
        for (int i = 0; i < 8; ++i) { e[i] = __expf(nz[i] - m); s += e[i]; }
#pragma unroll
        for (int off = 1; off <= 32; off <<= 1) s += __shfl_xor(s, off, 64);
        float inv = 1.f / s;
#pragma unroll
        for (int i = 0; i < 8; ++i) csl[i] = fmaxf(csl[i], e[i] * inv);
    }
#pragma unroll
    for (int i = 0; i < 8; ++i) s_csw[wv][lane * 8 + i] = csl[i];
    __syncthreads();
    if (tid < 512) {
        float c = s_csw[0][tid];
#pragma unroll
        for (int w = 1; w < 8; ++w) c = fmaxf(c, s_csw[w][tid]);
        s_cs[tid] = c;
        cs_out[b * 512 + tid] = c;
    }
    __syncthreads();
    // pooled partial sums: thread (jg, c8) covers l = jg+32t, channels c8*8..+7
    int jg = tid >> 4, c8 = tid & 15;   // jg 0..31
    if (c8 < 14) {
        f32x4 pa = {0.f, 0.f, 0.f, 0.f}, pb = {0.f, 0.f, 0.f, 0.f};
#pragma unroll 4
        for (int l = jg; l < 512; l += 32) {
            int row = s_x[l];
            float cv = s_cs[l];
            short8 e8 = *(const short8*)&embT[(size_t)row * 112 + c8 * 8];
#pragma unroll
            for (int r = 0; r < 4; ++r) {
                pa[r] += cv * bfu(e8[r]);
                pb[r] += cv * bfu(e8[4 + r]);
            }
        }
        *(f32x4*)&s_acc[jg][c8 * 8] = pa;
        *(f32x4*)&s_acc[jg][c8 * 8 + 4] = pb;
    }
    __syncthreads();
    if (tid < 112) {
        float p = 0.f;
#pragma unroll
        for (int g = 0; g < 32; ++g) p += s_acc[g][tid];
        s_pool[tid] = p * (1.f / 512.f);
    }
    __syncthreads();
    if (tid < 100) {
        float a = f1b[tid];
        for (int i = 0; i < 100; ++i) a += s_pool[i] * f1w[tid * 100 + i];
        s_h2[tid] = fmaxf(a, 0.f);
    }
    __syncthreads();
    float v = (tid < 100) ? s_h2[tid] * hw[tid] : 0.f;
#pragma unroll
    for (int off = 32; off >= 1; off >>= 1) v += __shfl_xor(v, off, 64);
    if (lane == 0) s_fin[wv] = v;
    __syncthreads();
    if (tid == 0) {
        float z = hb[0];
#pragma unroll
        for (int w = 0; w < 8; ++w) z += s_fin[w];
        out[b] = 1.f / (1.f + __expf(-z));
    }
}

// ---------------------------------------------------------------------------
extern "C" void kernel_launch(void* const* d_in, const int* in_sizes, int n_in,
                              void* d_out, int out_size, void* d_ws, size_t ws_size,
                              hipStream_t stream) {
    const int*   x   = (const int*)d_in[0];
    const float* u   = (const float*)d_in[1];
    const float* emb = (const float*)d_in[2];
    const float* c1w = (const float*)d_in[3];
    const float* c1b = (const float*)d_in[4];
    const float* giw = (const float*)d_in[5];
    const float* gib = (const float*)d_in[6];
    const float* c2w = (const float*)d_in[7];
    const float* c2b = (const float*)d_in[8];
    const float* liw = (const float*)d_in[9];
    const float* lib = (const float*)d_in[10];
    const float* c3w = (const float*)d_in[11];
    const float* c3b = (const float*)d_in[12];
    const float* c4w = (const float*)d_in[13];
    const float* c4b = (const float*)d_in[14];
    const float* f1w = (const float*)d_in[15];
    const float* f1b = (const float*)d_in[16];
    const float* hww = (const float*)d_in[17];
    const float* hbb = (const float*)d_in[18];
    float* out = (float*)d_out;

    char* ws = (char*)d_ws;
    short* locT   = (short*)(ws + 0);           // [512][512][112] bf16 (58.7 MB)
    short* embT   = (short*)(ws + 58720256);    // [100000][112] bf16 (22.4 MB)
    short* A1     = (short*)(ws + 81120256);    // 10*448*16 B each
    short* A2     = (short*)(ws + 81191936);
    short* A3     = (short*)(ws + 81263616);
    short* A4     = (short*)(ws + 81335296);    // 4*448*16 B
    float* logits = (float*)(ws + 81593344);    // [512][512]
    float* hpart  = (float*)(ws + 82641920);    // [512][8][2][112]
    float* giwT   = (float*)(ws + 86311936);    // [100][100]
    float* w3T    = (float*)(ws + 86351936);    // [100][100]

    prep_kernel<<<12740, 256, 0, stream>>>(emb, embT, c1w, c2w, liw, c3w, giw,
                                           A1, A2, A3, A4, giwT, w3T);

    size_t smemA = (size_t)2 * 72 * SSTR * 2;            // 39168 B
    fused_conv_kernel<<<dim3(8, 512), 256, smemA, stream>>>(
        x, embT, A1, A2, A3, c1b, c2b, lib, locT, hpart);
    conv3_logits_kernel<<<dim3(4, 512), 256, 0, stream>>>(
        locT, A4, hpart, giwT, gib, w3T, c3b, c4w, c4b, logits);
    samp_head_kernel<<<512, 512, 0, stream>>>(
        u, logits, x, embT, f1w, f1b, hww, hbb, out + 512, out);
}